// Round 3
// baseline (195.263 us; speedup 1.0000x reference)
//
#include <hip/hip_runtime.h>
#include <hip/hip_bf16.h>

// Shapes (fixed by reference): B=2, S=2048, D=1024, H=16, K(d_head)=64
// Inputs FP32, output FP32. Intermediates bf16 in d_ws (40 MB layout).
#define B_ 2
#define S_ 2048
#define D_ 1024
#define H_ 16
#define K_ 64
// BS = 4096, HK = 1024

// softmax scale folded into Q at projection time: 0.125 * log2(e)
#define QSCALE 0.18033688f

typedef __attribute__((ext_vector_type(4))) float f32x4;
typedef __attribute__((ext_vector_type(8))) short bf16x8;

__device__ __forceinline__ float bf_lo(unsigned int u) {
    union { float f; unsigned int i; } c; c.i = u << 16; return c.f;
}
__device__ __forceinline__ float bf_hi(unsigned int u) {
    union { float f; unsigned int i; } c; c.i = u & 0xffff0000u; return c.f;
}
__device__ __forceinline__ unsigned short f2b(float f) {
    __hip_bfloat16 h = __float2bfloat16(f);   // RNE
    union { __hip_bfloat16 h; unsigned short s; } c; c.h = h; return c.s;
}

// 2^x via v_exp_f32 (scale pre-folded into Q upstream)
__device__ __forceinline__ float fexp2(float x) {
#if __has_builtin(__builtin_amdgcn_exp2f)
    return __builtin_amdgcn_exp2f(x);
#else
    float r; asm("v_exp_f32 %0, %1" : "=v"(r) : "v"(x)); return r;
#endif
}

// Direct global->LDS, 16B per lane. LDS dest is wave-uniform base + lane*16
// (linear).
__device__ __forceinline__ void gl_lds16(const unsigned short* g, const unsigned short* l)
{
    __builtin_amdgcn_global_load_lds(
        (const __attribute__((address_space(1))) unsigned int*)(unsigned long long)g,
        (__attribute__((address_space(3))) unsigned int*)(unsigned int)(unsigned long long)l,
        16, 0, 0);
}

// ===========================================================================
// PREP KERNELS
// ===========================================================================

// fp32 -> bf16, 4 elems/thread.
__global__ __launch_bounds__(256) void cvt_bf16_4(
    const float* __restrict__ in, unsigned short* __restrict__ out)
{
    const int i = (blockIdx.x * 256 + threadIdx.x) * 4;
    const float4 v = *(const float4*)(in + i);
    ushort4 o;
    o.x = f2b(v.x); o.y = f2b(v.y); o.z = f2b(v.z); o.w = f2b(v.w);
    *(ushort4*)(out + i) = o;
}

// Transpose+convert: in fp32 [R][C] row-major -> out bf16 [C][R].
__global__ __launch_bounds__(256) void transpose_cvt3(
    const float* __restrict__ A0, const float* __restrict__ A1,
    const float* __restrict__ A2,
    unsigned short* __restrict__ O0, unsigned short* __restrict__ O1,
    unsigned short* __restrict__ O2,
    int R, int C, int mats_per_src)
{
    __shared__ float tl[64][65];
    const int z = blockIdx.z;
    const int src = z / mats_per_src, m = z - src * mats_per_src;
    const float* in = (src == 0) ? A0 : (src == 1) ? A1 : A2;
    unsigned short* out = (src == 0) ? O0 : (src == 1) ? O1 : O2;
    const size_t mb = (size_t)m * R * C;
    const int c0 = blockIdx.x * 64, r0 = blockIdx.y * 64;
    const int t = threadIdx.x;

    #pragma unroll
    for (int p = 0; p < 4; ++p) {
        const int idx = p * 256 + t;
        const int r = idx >> 4, cc = (idx & 15) * 4;
        const float4 v = *(const float4*)(in + mb + (size_t)(r0 + r) * C + c0 + cc);
        tl[r][cc] = v.x; tl[r][cc + 1] = v.y; tl[r][cc + 2] = v.z; tl[r][cc + 3] = v.w;
    }
    __syncthreads();
    const int c = t >> 2, rc = (t & 3) * 16;
    unsigned int u[8];
    #pragma unroll
    for (int j = 0; j < 8; ++j)
        u[j] = (unsigned int)f2b(tl[rc + 2 * j][c]) |
               ((unsigned int)f2b(tl[rc + 2 * j + 1][c]) << 16);
    unsigned short* op = out + mb + (size_t)(c0 + c) * R + r0 + rc;
    *(uint4*)op       = *(uint4*)&u[0];
    *(uint4*)(op + 8) = *(uint4*)&u[4];
}

// ===========================================================================
// Kernel A (MFMA): fused QKV projection.
// global_load_lds(16B) staging, linear LDS + XOR-swizzle (both sides),
// double-buffered tiles + prefetch (T3 2-phase).
// Q written PRE-SCALED by QSCALE. Q,K [B][H][S][K]; V transposed [B][H][K][S].
// ===========================================================================
__global__ __launch_bounds__(256) void gemm_qkv(
    const unsigned short* __restrict__ xb,    // bf16 [4096][1024]
    const unsigned short* __restrict__ Wtq,   // bf16 [16][64][1024]
    const unsigned short* __restrict__ Wtk,
    const unsigned short* __restrict__ Wtv,
    unsigned short* __restrict__ Qo,          // bf16 [B][H][S][K]
    unsigned short* __restrict__ Ko,          // bf16 [B][H][S][K]
    unsigned short* __restrict__ Vto)         // bf16 [B][H][K][S]
{
    __shared__ unsigned short xs[2][128 * 64];    // 32KB [m][k] linear, swz
    __shared__ unsigned short ws[2][3][64 * 64];  // 48KB [n][k] per W, swz

    const int h = blockIdx.x, mt = blockIdx.y;
    const int tid = threadIdx.x;
    const int wv = tid >> 6, lane = tid & 63;
    const int quad = lane >> 4, l15 = lane & 15;
    const int l8 = lane >> 3;
    const int c8 = ((lane & 7) ^ l8) * 8;   // pre-swizzled source col (elems)
    const int x7 = l15 & 7;                 // read-side XOR key
    const int m0 = mt * 128;

    const unsigned short* wsrc[3] = {
        Wtq + (size_t)h * 65536, Wtk + (size_t)h * 65536, Wtv + (size_t)h * 65536 };

    f32x4 acc[3][2][4] = {};   // [out][mfrag][nfrag]

    auto stage = [&](int bi, int k0) {
        const unsigned short* xg =
            xb + (size_t)(m0 + wv * 32 + l8) * 1024 + k0 + c8;
        #pragma unroll
        for (int j = 0; j < 4; ++j)
            gl_lds16(xg + (size_t)j * 8 * 1024, &xs[bi][(wv * 4 + j) * 512]);
        #pragma unroll
        for (int w = 0; w < 3; ++w) {
            const unsigned short* wg =
                wsrc[w] + (size_t)(wv * 16 + l8) * 1024 + k0 + c8;
            gl_lds16(wg,            &ws[bi][w][(wv * 2 + 0) * 512]);
            gl_lds16(wg + 8 * 1024, &ws[bi][w][(wv * 2 + 1) * 512]);
        }
    };

    stage(0, 0);
    __syncthreads();   // compiler emits vmcnt(0) drain here

    for (int kt = 0; kt < 16; ++kt) {
        const int cur = kt & 1;
        if (kt < 15) stage(cur ^ 1, (kt + 1) * 64);   // prefetch next tile

        const unsigned short* xsc = xs[cur];
        #pragma unroll
        for (int kh = 0; kh < 2; ++kh) {
            const int csw = ((kh * 4 + quad) ^ x7) * 8;   // rows used have r&7==x7
            const bf16x8 a0 = *(const bf16x8*)&xsc[(wv * 32 + l15) * 64 + csw];
            const bf16x8 a1 = *(const bf16x8*)&xsc[(wv * 32 + 16 + l15) * 64 + csw];
            #pragma unroll
            for (int nb = 0; nb < 4; ++nb) {
                #pragma unroll
                for (int w = 0; w < 3; ++w) {
                    const bf16x8 bfr = *(const bf16x8*)&ws[cur][w][(nb * 16 + l15) * 64 + csw];
                    acc[w][0][nb] = __builtin_amdgcn_mfma_f32_16x16x32_bf16(a0, bfr, acc[w][0][nb], 0, 0, 0);
                    acc[w][1][nb] = __builtin_amdgcn_mfma_f32_16x16x32_bf16(a1, bfr, acc[w][1][nb], 0, 0, 0);
                }
            }
        }
        __syncthreads();   // drains this iter's prefetch (issued pre-compute)
    }

    // Q (scaled), K epilogue: C row = quad*4+reg, col = l15. [B][H][S][K]
    #pragma unroll
    for (int mf = 0; mf < 2; ++mf)
        #pragma unroll
        for (int r = 0; r < 4; ++r) {
            const int s  = m0 + wv * 32 + mf * 16 + quad * 4 + r;
            const int bb = s >> 11;
            const int ss = s & (S_ - 1);
            const size_t base = (((size_t)(bb * H_ + h)) * S_ + ss) * K_;
            #pragma unroll
            for (int nb = 0; nb < 4; ++nb) {
                Qo[base + nb * 16 + l15] = f2b(acc[0][mf][nb][r] * QSCALE);
                Ko[base + nb * 16 + l15] = f2b(acc[1][mf][nb][r]);
            }
        }

    // V epilogue: write transposed. 4 consecutive s per lane -> 8B store.
    #pragma unroll
    for (int mf = 0; mf < 2; ++mf) {
        const int sb  = m0 + wv * 32 + mf * 16 + quad * 4;   // mult of 4
        const int bb  = sb >> 11;
        const int ss  = sb & (S_ - 1);
        #pragma unroll
        for (int nb = 0; nb < 4; ++nb) {
            const int k = nb * 16 + l15;
            const size_t vaddr = (((size_t)(bb * H_ + h)) * K_ + k) * S_ + ss;
            uint2 u;
            u.x = (unsigned int)f2b(acc[2][mf][nb][0]) | ((unsigned int)f2b(acc[2][mf][nb][1]) << 16);
            u.y = (unsigned int)f2b(acc[2][mf][nb][2]) | ((unsigned int)f2b(acc[2][mf][nb][3]) << 16);
            *(uint2*)&Vto[vaddr] = u;
        }
    }
}

// ===========================================================================
// Kernel B (MFMA flash attention v6):
// R2 post-mortem: dbuf prefetch was ~0 gain (65 µs flat); counters said
// latency-bound at 2 blocks/CU (Occ 18%). Fix = TLP not ILP:
// - 64 q-rows/block, qt=32 -> 1024 blocks = 4 blocks/CU (16 waves/CU).
// - single-buffered K/V: LDS 25.6KB (was 51KB) so 4 blocks fit.
// - bijective XCD swizzle: each XCD owns 4 complete (b,h) pairs -> K/V
//   working set 2MB < 4MB L2 (FETCH was 2.2x ideal; staging lat L2 not HBM).
// - Q pre-scaled upstream; p = 2^s; s_setprio around MFMA clusters.
// ===========================================================================
__global__ __launch_bounds__(256) void attn_mfma2(
    const unsigned short* __restrict__ Qb,
    const unsigned short* __restrict__ Kb,
    const unsigned short* __restrict__ Vt,   // [B][H][K][S]
    unsigned short* __restrict__ Cb)         // [B][S][H][K]
{
    __shared__ unsigned short ks[64 * 64];        // K tile [t][k] linear+swz
    __shared__ unsigned short vs[64 * 64];        // V^T tile [d][t] linear+swz
    __shared__ unsigned short pbuf[4 * 16 * 72];  // per-wave P [q][t], padded

    // XCD-aware bijective swizzle: nwg=1024, 8 XCDs, chunk=128.
    // XCD x gets logical ids [x*128,(x+1)*128) = 4 complete (b,h) pairs.
    const int bid = blockIdx.x;
    const int lid = (bid & 7) * 128 + (bid >> 3);
    const int qt  = lid & 31;
    const int bh  = lid >> 5;
    const int h   = bh & 15;
    const int b   = bh >> 4;

    const int tid  = threadIdx.x;
    const int wv = tid >> 6, lane = tid & 63;
    const int quad = lane >> 4, l15 = lane & 15;
    const int l8 = lane >> 3;
    const int c8 = ((lane & 7) ^ l8) * 8;
    const int x7 = l15 & 7;

    const size_t base = ((size_t)(b * H_ + h)) * S_ * K_;   // Q,K and Vt extent

    // Q fragments: wave owns 16 q-rows (B-operand of swapped QK^T)
    const int qrow = qt * 64 + wv * 16 + l15;
    const bf16x8 qf0 = *(const bf16x8*)(Qb + base + (size_t)qrow * K_ + quad * 8);
    const bf16x8 qf1 = *(const bf16x8*)(Qb + base + (size_t)qrow * K_ + 32 + quad * 8);

    f32x4 ctxa[4] = {};
    float li = 0.0f;    // row-sum for q = l15 (replicated across quads)

    unsigned short* pw = pbuf + wv * (16 * 72);

    for (int it = 0; it < S_ / 64; ++it) {
        const int t0 = it * 64;
        __syncthreads();   // previous tile's reads complete before overwrite
        {
            const unsigned short* kg =
                Kb + base + (size_t)(t0 + wv * 16 + l8) * K_ + c8;
            gl_lds16(kg,          &ks[(wv * 2 + 0) * 512]);
            gl_lds16(kg + 8 * K_, &ks[(wv * 2 + 1) * 512]);
            const unsigned short* vg =
                Vt + base + (size_t)(wv * 16 + l8) * S_ + t0 + c8;
            gl_lds16(vg,          &vs[(wv * 2 + 0) * 512]);
            gl_lds16(vg + 8 * S_, &vs[(wv * 2 + 1) * 512]);
        }
        __syncthreads();   // vmcnt(0) drain (other resident blocks hide this)

        // ---- S^T = K·Q^T : lane holds S[t=16tb+quad*4+r][q=l15] ----
        f32x4 sac[4] = {};
        __builtin_amdgcn_s_setprio(1);
        #pragma unroll
        for (int tb = 0; tb < 4; ++tb) {
            const bf16x8 kf0 = *(const bf16x8*)&ks[(tb * 16 + l15) * 64 + ((quad) ^ x7) * 8];
            const bf16x8 kf1 = *(const bf16x8*)&ks[(tb * 16 + l15) * 64 + ((4 + quad) ^ x7) * 8];
            sac[tb] = __builtin_amdgcn_mfma_f32_16x16x32_bf16(kf0, qf0, sac[tb], 0, 0, 0);
            sac[tb] = __builtin_amdgcn_mfma_f32_16x16x32_bf16(kf1, qf1, sac[tb], 0, 0, 0);
        }
        __builtin_amdgcn_s_setprio(0);

        // ---- softmax: p = 2^s; in-lane sum + cross-quad ----
        float ps[4][4];
        float rs = 0.0f;
        #pragma unroll
        for (int tb = 0; tb < 4; ++tb)
            #pragma unroll
            for (int r = 0; r < 4; ++r) {
                const float p = fexp2(sac[tb][r]);
                ps[tb][r] = p;
                rs += p;
            }
        rs += __shfl_xor(rs, 16);
        rs += __shfl_xor(rs, 32);
        li += rs;

        // ---- P -> pw[q][t]: 4 consecutive t per lane => b64 writes ----
        #pragma unroll
        for (int tb = 0; tb < 4; ++tb) {
            uint2 u;
            u.x = (unsigned int)f2b(ps[tb][0]) | ((unsigned int)f2b(ps[tb][1]) << 16);
            u.y = (unsigned int)f2b(ps[tb][2]) | ((unsigned int)f2b(ps[tb][3]) << 16);
            *(uint2*)&pw[l15 * 72 + tb * 16 + quad * 4] = u;
        }

        // ---- PV: ctx[q][d], A = P rows (pw), B = V^T rows (vs) ----
        __builtin_amdgcn_s_setprio(1);
        #pragma unroll
        for (int kh = 0; kh < 2; ++kh) {
            const bf16x8 af = *(const bf16x8*)&pw[l15 * 72 + kh * 32 + quad * 8];
            #pragma unroll
            for (int cb = 0; cb < 4; ++cb) {
                const bf16x8 bfr = *(const bf16x8*)&vs[(cb * 16 + l15) * 64 + ((kh * 4 + quad) ^ x7) * 8];
                ctxa[cb] = __builtin_amdgcn_mfma_f32_16x16x32_bf16(af, bfr, ctxa[cb], 0, 0, 0);
            }
        }
        __builtin_amdgcn_s_setprio(0);
    }

    // ---- epilogue: normalize (li fetched from lane q), write [bs][hk] ----
    #pragma unroll
    for (int r = 0; r < 4; ++r) {
        const float inv = 1.0f / __shfl(li, quad * 4 + r);
        const int s = qt * 64 + wv * 16 + quad * 4 + r;
        const size_t ob = (((size_t)(b * S_ + s)) * H_ + h) * K_;
        #pragma unroll
        for (int cb = 0; cb < 4; ++cb)
            Cb[ob + cb * 16 + l15] = f2b(ctxa[cb][r] * inv);
    }
}

// ===========================================================================
// Fallback attention (R5-verified): reads V [B][H][S][K], in-kernel
// transpose, running-max softmax. (Expects UNSCALED Q from qkv_proj.)
// ===========================================================================
__global__ __launch_bounds__(256) void attn_mfma_v1(
    const unsigned short* __restrict__ Qb,
    const unsigned short* __restrict__ Kb,
    const unsigned short* __restrict__ Vb,
    unsigned short* __restrict__ Cb)
{
    __shared__ unsigned short ks[64 * 72];
    __shared__ unsigned short vt[64 * 72];
    __shared__ unsigned short pbuf[4 * 16 * 72];

    const int b = blockIdx.z, h = blockIdx.y, qt = blockIdx.x;
    const int tid  = threadIdx.x;
    const int wave = tid >> 6, lane = tid & 63;
    const int quad = lane >> 4, l15 = lane & 15;

    const size_t base = ((size_t)(b * H_ + h)) * S_ * K_;

    const int qrow = qt * 64 + wave * 16 + l15;
    const bf16x8 qf0 = *(const bf16x8*)(Qb + base + (size_t)qrow * K_ + quad * 8);
    const bf16x8 qf1 = *(const bf16x8*)(Qb + base + (size_t)qrow * K_ + 32 + quad * 8);

    f32x4 ctxa[4] = {};
    float mi[4], li[4];
    #pragma unroll
    for (int r = 0; r < 4; ++r) { mi[r] = -INFINITY; li[r] = 0.0f; }

    unsigned short* pw = pbuf + wave * 16 * 72;

    for (int tb0 = 0; tb0 < S_; tb0 += 64) {
        __syncthreads();
        #pragma unroll
        for (int p = 0; p < 2; ++p) {
            const int idx = tid + p * 256;
            const int t = idx >> 3, c = idx & 7;
            *(uint4*)&ks[t * 72 + c * 8] =
                *(const uint4*)(Kb + base + (size_t)(tb0 + t) * K_ + c * 8);
        }
        #pragma unroll
        for (int p = 0; p < 2; ++p) {
            const int c = wave + p * 4;
            uint4 u = *(const uint4*)(Vb + base + (size_t)(tb0 + lane) * K_ + c * 8);
            const unsigned short* us = (const unsigned short*)&u;
            #pragma unroll
            for (int d = 0; d < 8; ++d)
                vt[(c * 8 + d) * 72 + lane] = us[d];
        }
        __syncthreads();

        f32x4 sac[4] = {};
        #pragma unroll
        for (int tb = 0; tb < 4; ++tb) {
            const bf16x8 kf0 = *(const bf16x8*)&ks[(tb * 16 + l15) * 72 + quad * 8];
            const bf16x8 kf1 = *(const bf16x8*)&ks[(tb * 16 + l15) * 72 + 32 + quad * 8];
            sac[tb] = __builtin_amdgcn_mfma_f32_16x16x32_bf16(qf0, kf0, sac[tb], 0, 0, 0);
            sac[tb] = __builtin_amdgcn_mfma_f32_16x16x32_bf16(qf1, kf1, sac[tb], 0, 0, 0);
        }

        float mnew[4], alpha[4];
        #pragma unroll
        for (int r = 0; r < 4; ++r) {
            float v = fmaxf(fmaxf(sac[0][r], sac[1][r]), fmaxf(sac[2][r], sac[3][r])) * 0.125f;
            v = fmaxf(v, __shfl_xor(v, 1));
            v = fmaxf(v, __shfl_xor(v, 2));
            v = fmaxf(v, __shfl_xor(v, 4));
            v = fmaxf(v, __shfl_xor(v, 8));
            mnew[r]  = fmaxf(mi[r], v);
            alpha[r] = __expf(mi[r] - mnew[r]);
            mi[r]    = mnew[r];
        }
        float pv[4][4], rs[4];
        #pragma unroll
        for (int r = 0; r < 4; ++r) rs[r] = 0.0f;
        #pragma unroll
        for (int tb = 0; tb < 4; ++tb)
            #pragma unroll
            for (int r = 0; r < 4; ++r) {
                const float p = __expf(sac[tb][r] * 0.125f - mnew[r]);
                pv[tb][r] = p;
                rs[r] += p;
            }
        #pragma unroll
        for (int r = 0; r < 4; ++r) {
            float s = rs[r];
            s += __shfl_xor(s, 1);
            s += __shfl_xor(s, 2);
            s += __shfl_xor(s, 4);
            s += __shfl_xor(s, 8);
            li[r] = li[r] * alpha[r] + s;
        }
        #pragma unroll
        for (int cb = 0; cb < 4; ++cb)
            #pragma unroll
            for (int r = 0; r < 4; ++r)
                ctxa[cb][r] *= alpha[r];

        #pragma unroll
        for (int tb = 0; tb < 4; ++tb)
            #pragma unroll
            for (int r = 0; r < 4; ++r)
                pw[(quad * 4 + r) * 72 + tb * 16 + l15] = f2b(pv[tb][r]);

        #pragma unroll
        for (int kh = 0; kh < 2; ++kh) {
            const bf16x8 af = *(const bf16x8*)&pw[l15 * 72 + kh * 32 + quad * 8];
            #pragma unroll
            for (int cb = 0; cb < 4; ++cb) {
                const bf16x8 bfr = *(const bf16x8*)&vt[(cb * 16 + l15) * 72 + kh * 32 + quad * 8];
                ctxa[cb] = __builtin_amdgcn_mfma_f32_16x16x32_bf16(af, bfr, ctxa[cb], 0, 0, 0);
            }
        }
    }

    #pragma unroll
    for (int r = 0; r < 4; ++r) {
        const float inv = 1.0f / li[r];
        const int s = qt * 64 + wave * 16 + quad * 4 + r;
        const size_t ob = (((size_t)(b * S_ + s)) * H_ + h) * K_;
        #pragma unroll
        for (int cb = 0; cb < 4; ++cb)
            Cb[ob + cb * 16 + l15] = f2b(ctxa[cb][r] * inv);
    }
}

// ===========================================================================
// Kernel C (MFMA): output projection + head sum.
// global_load_lds(16B) staging + double-buffer/prefetch (T3 2-phase).
// ===========================================================================
__global__ __launch_bounds__(256) void gemm_out(
    const unsigned short* __restrict__ ctx,   // bf16 [4096][1024]
    const unsigned short* __restrict__ Wot,   // bf16 [1024 d][1024 hk]
    float* __restrict__ out)                  // fp32 [4096][1024]
{
    __shared__ unsigned short cs[2][128 * 64];   // 32KB
    __shared__ unsigned short ws[2][64 * 64];    // 16KB

    const int nt = blockIdx.x, mt = blockIdx.y;
    const int tid = threadIdx.x;
    const int wv = tid >> 6, lane = tid & 63;
    const int quad = lane >> 4, l15 = lane & 15;
    const int l8 = lane >> 3;
    const int c8 = ((lane & 7) ^ l8) * 8;
    const int x7 = l15 & 7;
    const int m0 = mt * 128, n0 = nt * 64;

    f32x4 acc[2][4] = {};

    auto stage = [&](int bi, int k0) {
        const unsigned short* cg =
            ctx + (size_t)(m0 + wv * 32 + l8) * 1024 + k0 + c8;
        #pragma unroll
        for (int j = 0; j < 4; ++j)
            gl_lds16(cg + (size_t)j * 8 * 1024, &cs[bi][(wv * 4 + j) * 512]);
        const unsigned short* wg =
            Wot + (size_t)(n0 + wv * 16 + l8) * 1024 + k0 + c8;
        gl_lds16(wg,            &ws[bi][(wv * 2 + 0) * 512]);
        gl_lds16(wg + 8 * 1024, &ws[bi][(wv * 2 + 1) * 512]);
    };

    stage(0, 0);
    __syncthreads();

    for (int kt = 0; kt < 16; ++kt) {
        const int cur = kt & 1;
        if (kt < 15) stage(cur ^ 1, (kt + 1) * 64);

        const unsigned short* csc = cs[cur];
        const unsigned short* wsc = ws[cur];
        #pragma unroll
        for (int kh = 0; kh < 2; ++kh) {
            const int csw = ((kh * 4 + quad) ^ x7) * 8;
            const bf16x8 a0 = *(const bf16x8*)&csc[(wv * 32 + l15) * 64 + csw];
            const bf16x8 a1 = *(const bf16x8*)&csc[(wv * 32 + 16 + l15) * 64 + csw];
            #pragma unroll
            for (int nb = 0; nb < 4; ++nb) {
                const bf16x8 bfr = *(const bf16x8*)&wsc[(nb * 16 + l15) * 64 + csw];
                acc[0][nb] = __builtin_amdgcn_mfma_f32_16x16x32_bf16(a0, bfr, acc[0][nb], 0, 0, 0);
                acc[1][nb] = __builtin_amdgcn_mfma_f32_16x16x32_bf16(a1, bfr, acc[1][nb], 0, 0, 0);
            }
        }
        __syncthreads();
    }

    #pragma unroll
    for (int mf = 0; mf < 2; ++mf)
        #pragma unroll
        for (int r = 0; r < 4; ++r) {
            const int m = m0 + wv * 32 + mf * 16 + quad * 4 + r;
            #pragma unroll
            for (int nb = 0; nb < 4; ++nb)
                out[(size_t)m * 1024 + n0 + nb * 16 + l15] = acc[mf][nb][r];
        }
}

// ===========================================================================
// FALLBACK (32 MB ws): fp32 VALU projections (R5-verified)
// ===========================================================================
__global__ __launch_bounds__(256) void qkv_proj(
    const float* __restrict__ x, const float* __restrict__ Wq,
    const float* __restrict__ Wk, const float* __restrict__ Wv,
    unsigned short* __restrict__ Qo, unsigned short* __restrict__ Ko,
    unsigned short* __restrict__ Vo)
{
    __shared__ float xs[32][68];
    __shared__ float wqs[32][68];
    __shared__ float wks[32][68];
    __shared__ float wvs[32][68];

    const int h  = blockIdx.x;
    const int m0 = blockIdx.y * 64;
    const int t  = threadIdx.x;
    const int tx = t & 15, ty = t >> 4;
    const int xr = t >> 2, xc = (t & 3) * 8;
    const int wr = t >> 3, wc = (t & 7) * 8;

    float aq[4][4] = {}, ak[4][4] = {}, av[4][4] = {};
    const int wbase = h * D_ * K_;

    for (int d0 = 0; d0 < D_; d0 += 32) {
        __syncthreads();
        {
            const float* xf = x + (size_t)(m0 + xr) * D_ + d0 + xc;
            const float4 a = *(const float4*)xf;
            const float4 b = *(const float4*)(xf + 4);
            xs[xc + 0][xr] = a.x; xs[xc + 1][xr] = a.y;
            xs[xc + 2][xr] = a.z; xs[xc + 3][xr] = a.w;
            xs[xc + 4][xr] = b.x; xs[xc + 5][xr] = b.y;
            xs[xc + 6][xr] = b.z; xs[xc + 7][xr] = b.w;
        }
        {
            const size_t idx = (size_t)wbase + (size_t)(d0 + wr) * K_ + wc;
            *(float4*)&wqs[wr][wc]     = *(const float4*)&Wq[idx];
            *(float4*)&wqs[wr][wc + 4] = *(const float4*)&Wq[idx + 4];
            *(float4*)&wks[wr][wc]     = *(const float4*)&Wk[idx];
            *(float4*)&wks[wr][wc + 4] = *(const float4*)&Wk[idx + 4];
            *(float4*)&wvs[wr][wc]     = *(const float4*)&Wv[idx];
            *(float4*)&wvs[wr][wc + 4] = *(const float4*)&Wv[idx + 4];
        }
        __syncthreads();

        #pragma unroll 8
        for (int kk = 0; kk < 32; ++kk) {
            const float4 xv = *(const float4*)&xs[kk][ty * 4];
            const float4 q4 = *(const float4*)&wqs[kk][tx * 4];
            const float4 k4 = *(const float4*)&wks[kk][tx * 4];
            const float4 v4 = *(const float4*)&wvs[kk][tx * 4];
            const float xa[4] = {xv.x, xv.y, xv.z, xv.w};
            const float qa[4] = {q4.x, q4.y, q4.z, q4.w};
            const float ka[4] = {k4.x, k4.y, k4.z, k4.w};
            const float va[4] = {v4.x, v4.y, v4.z, v4.w};
            #pragma unroll
            for (int i = 0; i < 4; ++i)
                #pragma unroll
                for (int j = 0; j < 4; ++j) {
                    aq[i][j] += xa[i] * qa[j];
                    ak[i][j] += xa[i] * ka[j];
                    av[i][j] += xa[i] * va[j];
                }
        }
    }

    #pragma unroll
    for (int i = 0; i < 4; ++i) {
        const int m  = m0 + ty * 4 + i;
        const int bb = m >> 11;
        const int ss = m & (S_ - 1);
        const size_t base = (((size_t)(bb * H_ + h)) * S_ + ss) * K_ + tx * 4;
        ushort4 pq, pk, pv;
        pq.x = f2b(aq[i][0]); pq.y = f2b(aq[i][1]); pq.z = f2b(aq[i][2]); pq.w = f2b(aq[i][3]);
        pk.x = f2b(ak[i][0]); pk.y = f2b(ak[i][1]); pk.z = f2b(ak[i][2]); pk.w = f2b(ak[i][3]);
        pv.x = f2b(av[i][0]); pv.y = f2b(av[i][1]); pv.z = f2b(av[i][2]); pv.w = f2b(av[i][3]);
        *(ushort4*)&Qo[base] = pq;
        *(ushort4*)&Ko[base] = pk;
        *(ushort4*)&Vo[base] = pv;
    }
}

__global__ __launch_bounds__(256) void out_proj(
    const unsigned int* __restrict__ Cb, const float* __restrict__ Wo,
    float* __restrict__ out)
{
    __shared__ float cs[32][68];
    __shared__ float wos[32][68];

    const int n0 = blockIdx.x * 64;
    const int m0 = blockIdx.y * 64;
    const int t  = threadIdx.x;
    const int tx = t & 15, ty = t >> 4;
    const int xr = t >> 2, xc = (t & 3) * 8;
    const int wr = t >> 3, wc = (t & 7) * 8;

    float acc[4][4] = {};

    for (int k0 = 0; k0 < 1024; k0 += 32) {
        __syncthreads();
        {
            uint4 u = *(const uint4*)&Cb[((size_t)(m0 + xr) * 1024 + k0 + xc) >> 1];
            cs[xc + 0][xr] = bf_lo(u.x); cs[xc + 1][xr] = bf_hi(u.x);
            cs[xc + 2][xr] = bf_lo(u.y); cs[xc + 3][xr] = bf_hi(u.y);
            cs[xc + 4][xr] = bf_lo(u.z); cs[xc + 5][xr] = bf_hi(u.z);
            cs[xc + 6][xr] = bf_lo(u.w); cs[xc + 7][xr] = bf_hi(u.w);
        }
        {
            const float* wof = Wo + (size_t)(k0 + wr) * 1024 + n0 + wc;
            *(float4*)&wos[wr][wc]     = *(const float4*)wof;
            *(float4*)&wos[wr][wc + 4] = *(const float4*)(wof + 4);
        }
        __syncthreads();

        #pragma unroll 8
        for (int kk = 0; kk < 32; ++kk) {
            const float4 cv = *(const float4*)&cs[kk][ty * 4];
            const float4 wv = *(const float4*)&wos[kk][tx * 4];
            const float ca[4] = {cv.x, cv.y, cv.z, cv.w};
            const float wa[4] = {wv.x, wv.y, wv.z, wv.w};
            #pragma unroll
            for (int i = 0; i < 4; ++i)
                #pragma unroll
                for (int j = 0; j < 4; ++j)
                    acc[i][j] += ca[i] * wa[j];
        }
    }

    #pragma unroll
    for (int i = 0; i < 4; ++i) {
        const int m = m0 + ty * 4 + i;
        float4 p = make_float4(acc[i][0], acc[i][1], acc[i][2], acc[i][3]);
        *(float4*)&out[(size_t)m * 1024 + n0 + tx * 4] = p;
    }
}

// ===========================================================================
extern "C" void kernel_launch(void* const* d_in, const int* in_sizes, int n_in,
                              void* d_out, int out_size, void* d_ws, size_t ws_size,
                              hipStream_t stream)
{
    (void)in_sizes; (void)n_in; (void)out_size;
    const float* x  = (const float*)d_in[0];
    const float* Wq = (const float*)d_in[1];
    const float* Wk = (const float*)d_in[2];
    const float* Wv = (const float*)d_in[3];
    const float* Wo = (const float*)d_in[4];
    float* out = (float*)d_out;

    const size_t QKV_ELEMS = (size_t)B_ * H_ * S_ * K_;   // 4,194,304

    if (ws_size >= (size_t)40 * 1024 * 1024) {
        // ws layout (bf16 elems), exactly 40 MB:
        //  xb (8MB; aliased by ctx after gemm_qkv) | Wtq|Wtk|Wtv (2MB each) |
        //  Wot (2MB) | Q (8MB) | K (8MB) | Vt (8MB, [B][H][K][S])
        unsigned short* xb  = (unsigned short*)d_ws;
        unsigned short* Wtq = xb  + (size_t)4096 * 1024;
        unsigned short* Wtk = Wtq + (size_t)16 * 64 * 1024;
        unsigned short* Wtv = Wtk + (size_t)16 * 64 * 1024;
        unsigned short* Wot = Wtv + (size_t)16 * 64 * 1024;
        unsigned short* Qb  = Wot + (size_t)1024 * 1024;
        unsigned short* Kb  = Qb + QKV_ELEMS;
        unsigned short* Vtb = Kb + QKV_ELEMS;
        unsigned short* Cb  = xb;   // alias: xb dead after gemm_qkv

        cvt_bf16_4<<<4096, 256, 0, stream>>>(x, xb);
        transpose_cvt3<<<dim3(1, 16, 48), 256, 0, stream>>>(
            Wq, Wk, Wv, Wtq, Wtk, Wtv, 1024, 64, 16);
        transpose_cvt3<<<dim3(16, 16, 1), 256, 0, stream>>>(
            Wo, Wo, Wo, Wot, Wot, Wot, 1024, 1024, 1);

        gemm_qkv<<<dim3(16, 32), 256, 0, stream>>>(xb, Wtq, Wtk, Wtv, Qb, Kb, Vtb);
        attn_mfma2<<<dim3(1024), 256, 0, stream>>>(Qb, Kb, Vtb, Cb);
        gemm_out<<<dim3(16, 32), 256, 0, stream>>>(Cb, Wot, out);
    } else {
        // fallback (32 MB): Q | K | V | ctx   (R5-verified path)
        unsigned short* Qb = (unsigned short*)d_ws;
        unsigned short* Kb = Qb + QKV_ELEMS;
        unsigned short* Vb = Kb + QKV_ELEMS;
        unsigned short* Cb = Vb + QKV_ELEMS;

        qkv_proj<<<dim3(16, 64), 256, 0, stream>>>(x, Wq, Wk, Wv, Qb, Kb, Vb);
        attn_mfma_v1<<<dim3(32, 16, 2), 256, 0, stream>>>(Qb, Kb, Vb, Cb);
        out_proj<<<dim3(16, 64), 256, 0, stream>>>((const unsigned int*)Cb, Wo, out);
    }
}

// Round 4
// 186.156 us; speedup vs baseline: 1.0489x; 1.0489x over previous
//
#include <hip/hip_runtime.h>
#include <hip/hip_bf16.h>

// Shapes (fixed by reference): B=2, S=2048, D=1024, H=16, K(d_head)=64
// Inputs FP32, output FP32. Intermediates bf16 in d_ws (40 MB layout).
#define B_ 2
#define S_ 2048
#define D_ 1024
#define H_ 16
#define K_ 64
// BS = 4096, HK = 1024

// softmax scale folded into Q at projection time: 0.125 * log2(e)
#define QSCALE 0.18033688f

typedef __attribute__((ext_vector_type(4))) float f32x4;
typedef __attribute__((ext_vector_type(8))) short bf16x8;

__device__ __forceinline__ float bf_lo(unsigned int u) {
    union { float f; unsigned int i; } c; c.i = u << 16; return c.f;
}
__device__ __forceinline__ float bf_hi(unsigned int u) {
    union { float f; unsigned int i; } c; c.i = u & 0xffff0000u; return c.f;
}
__device__ __forceinline__ unsigned short f2b(float f) {
    __hip_bfloat16 h = __float2bfloat16(f);   // RNE
    union { __hip_bfloat16 h; unsigned short s; } c; c.h = h; return c.s;
}

// 2^x via v_exp_f32 (scale pre-folded into Q upstream)
__device__ __forceinline__ float fexp2(float x) {
#if __has_builtin(__builtin_amdgcn_exp2f)
    return __builtin_amdgcn_exp2f(x);
#else
    float r; asm("v_exp_f32 %0, %1" : "=v"(r) : "v"(x)); return r;
#endif
}

// Direct global->LDS, 16B per lane. LDS dest is wave-uniform base + lane*16
// (linear).
__device__ __forceinline__ void gl_lds16(const unsigned short* g, const unsigned short* l)
{
    __builtin_amdgcn_global_load_lds(
        (const __attribute__((address_space(1))) unsigned int*)(unsigned long long)g,
        (__attribute__((address_space(3))) unsigned int*)(unsigned int)(unsigned long long)l,
        16, 0, 0);
}

// ===========================================================================
// PREP KERNELS
// ===========================================================================

// fp32 -> bf16, 4 elems/thread.
__global__ __launch_bounds__(256) void cvt_bf16_4(
    const float* __restrict__ in, unsigned short* __restrict__ out)
{
    const int i = (blockIdx.x * 256 + threadIdx.x) * 4;
    const float4 v = *(const float4*)(in + i);
    ushort4 o;
    o.x = f2b(v.x); o.y = f2b(v.y); o.z = f2b(v.z); o.w = f2b(v.w);
    *(ushort4*)(out + i) = o;
}

// Transpose+convert: in fp32 [R][C] row-major -> out bf16 [C][R].
__global__ __launch_bounds__(256) void transpose_cvt3(
    const float* __restrict__ A0, const float* __restrict__ A1,
    const float* __restrict__ A2,
    unsigned short* __restrict__ O0, unsigned short* __restrict__ O1,
    unsigned short* __restrict__ O2,
    int R, int C, int mats_per_src)
{
    __shared__ float tl[64][65];
    const int z = blockIdx.z;
    const int src = z / mats_per_src, m = z - src * mats_per_src;
    const float* in = (src == 0) ? A0 : (src == 1) ? A1 : A2;
    unsigned short* out = (src == 0) ? O0 : (src == 1) ? O1 : O2;
    const size_t mb = (size_t)m * R * C;
    const int c0 = blockIdx.x * 64, r0 = blockIdx.y * 64;
    const int t = threadIdx.x;

    #pragma unroll
    for (int p = 0; p < 4; ++p) {
        const int idx = p * 256 + t;
        const int r = idx >> 4, cc = (idx & 15) * 4;
        const float4 v = *(const float4*)(in + mb + (size_t)(r0 + r) * C + c0 + cc);
        tl[r][cc] = v.x; tl[r][cc + 1] = v.y; tl[r][cc + 2] = v.z; tl[r][cc + 3] = v.w;
    }
    __syncthreads();
    const int c = t >> 2, rc = (t & 3) * 16;
    unsigned int u[8];
    #pragma unroll
    for (int j = 0; j < 8; ++j)
        u[j] = (unsigned int)f2b(tl[rc + 2 * j][c]) |
               ((unsigned int)f2b(tl[rc + 2 * j + 1][c]) << 16);
    unsigned short* op = out + mb + (size_t)(c0 + c) * R + r0 + rc;
    *(uint4*)op       = *(uint4*)&u[0];
    *(uint4*)(op + 8) = *(uint4*)&u[4];
}

// ===========================================================================
// Kernel A (MFMA): fused QKV projection.
// global_load_lds(16B) staging, linear LDS + XOR-swizzle (both sides),
// double-buffered tiles + prefetch (T3 2-phase).
// Q written PRE-SCALED by QSCALE. Q,K [B][H][S][K].
// V written transposed AND k-permuted within 32-col blocks (Vtp):
//   store pos kappa of value t: kappa{4:3}=t{3:2}, kappa{2}=t{4}, kappa{1:0}=t{1:0}
// so attn's PV A-operand is lane-local (P never goes through LDS).
// ===========================================================================
__global__ __launch_bounds__(256) void gemm_qkv(
    const unsigned short* __restrict__ xb,    // bf16 [4096][1024]
    const unsigned short* __restrict__ Wtq,   // bf16 [16][64][1024]
    const unsigned short* __restrict__ Wtk,
    const unsigned short* __restrict__ Wtv,
    unsigned short* __restrict__ Qo,          // bf16 [B][H][S][K]
    unsigned short* __restrict__ Ko,          // bf16 [B][H][S][K]
    unsigned short* __restrict__ Vto)         // bf16 [B][H][K][S] (permuted)
{
    __shared__ unsigned short xs[2][128 * 64];    // 32KB [m][k] linear, swz
    __shared__ unsigned short ws[2][3][64 * 64];  // 48KB [n][k] per W, swz

    const int h = blockIdx.x, mt = blockIdx.y;
    const int tid = threadIdx.x;
    const int wv = tid >> 6, lane = tid & 63;
    const int quad = lane >> 4, l15 = lane & 15;
    const int l8 = lane >> 3;
    const int c8 = ((lane & 7) ^ l8) * 8;   // pre-swizzled source col (elems)
    const int x7 = l15 & 7;                 // read-side XOR key
    const int m0 = mt * 128;

    const unsigned short* wsrc[3] = {
        Wtq + (size_t)h * 65536, Wtk + (size_t)h * 65536, Wtv + (size_t)h * 65536 };

    f32x4 acc[3][2][4] = {};   // [out][mfrag][nfrag]

    auto stage = [&](int bi, int k0) {
        const unsigned short* xg =
            xb + (size_t)(m0 + wv * 32 + l8) * 1024 + k0 + c8;
        #pragma unroll
        for (int j = 0; j < 4; ++j)
            gl_lds16(xg + (size_t)j * 8 * 1024, &xs[bi][(wv * 4 + j) * 512]);
        #pragma unroll
        for (int w = 0; w < 3; ++w) {
            const unsigned short* wg =
                wsrc[w] + (size_t)(wv * 16 + l8) * 1024 + k0 + c8;
            gl_lds16(wg,            &ws[bi][w][(wv * 2 + 0) * 512]);
            gl_lds16(wg + 8 * 1024, &ws[bi][w][(wv * 2 + 1) * 512]);
        }
    };

    stage(0, 0);
    __syncthreads();   // compiler emits vmcnt(0) drain here

    for (int kt = 0; kt < 16; ++kt) {
        const int cur = kt & 1;
        if (kt < 15) stage(cur ^ 1, (kt + 1) * 64);   // prefetch next tile

        const unsigned short* xsc = xs[cur];
        #pragma unroll
        for (int kh = 0; kh < 2; ++kh) {
            const int csw = ((kh * 4 + quad) ^ x7) * 8;   // rows used have r&7==x7
            const bf16x8 a0 = *(const bf16x8*)&xsc[(wv * 32 + l15) * 64 + csw];
            const bf16x8 a1 = *(const bf16x8*)&xsc[(wv * 32 + 16 + l15) * 64 + csw];
            #pragma unroll
            for (int nb = 0; nb < 4; ++nb) {
                #pragma unroll
                for (int w = 0; w < 3; ++w) {
                    const bf16x8 bfr = *(const bf16x8*)&ws[cur][w][(nb * 16 + l15) * 64 + csw];
                    acc[w][0][nb] = __builtin_amdgcn_mfma_f32_16x16x32_bf16(a0, bfr, acc[w][0][nb], 0, 0, 0);
                    acc[w][1][nb] = __builtin_amdgcn_mfma_f32_16x16x32_bf16(a1, bfr, acc[w][1][nb], 0, 0, 0);
                }
            }
        }
        __syncthreads();   // drains this iter's prefetch (issued pre-compute)
    }

    // Q (scaled), K epilogue: C row = quad*4+reg, col = l15. [B][H][S][K]
    #pragma unroll
    for (int mf = 0; mf < 2; ++mf)
        #pragma unroll
        for (int r = 0; r < 4; ++r) {
            const int s  = m0 + wv * 32 + mf * 16 + quad * 4 + r;
            const int bb = s >> 11;
            const int ss = s & (S_ - 1);
            const size_t base = (((size_t)(bb * H_ + h)) * S_ + ss) * K_;
            #pragma unroll
            for (int nb = 0; nb < 4; ++nb) {
                Qo[base + nb * 16 + l15] = f2b(acc[0][mf][nb][r] * QSCALE);
                Ko[base + nb * 16 + l15] = f2b(acc[1][mf][nb][r]);
            }
        }

    // V epilogue: transposed + k-permuted. Lane's 4 consecutive s values
    // (s = sb + r, sb = ...+quad*4, r=0..3) land at permuted inner pos
    // kappa = quad*8 + mf*4 + r within the 32-block -> still one 8B store.
    {
        const int sb32 = m0 + wv * 32;           // 32-aligned block base
        const int bb   = sb32 >> 11;
        const int ssb  = sb32 & (S_ - 1);        // 32-aligned
        #pragma unroll
        for (int mf = 0; mf < 2; ++mf) {
            const int kap = quad * 8 + mf * 4;   // permuted offset in 32-block
            #pragma unroll
            for (int nb = 0; nb < 4; ++nb) {
                const int k = nb * 16 + l15;
                const size_t vaddr = (((size_t)(bb * H_ + h)) * K_ + k) * S_ + ssb + kap;
                uint2 u;
                u.x = (unsigned int)f2b(acc[2][mf][nb][0]) | ((unsigned int)f2b(acc[2][mf][nb][1]) << 16);
                u.y = (unsigned int)f2b(acc[2][mf][nb][2]) | ((unsigned int)f2b(acc[2][mf][nb][3]) << 16);
                *(uint2*)&Vto[vaddr] = u;
            }
        }
    }
}

// ===========================================================================
// Kernel B (MFMA flash attention v7):
// R3 post-mortem: LDS-throughput-bound (2x occupancy -> 0 gain; byte math
// matches dur). This version cuts LDS bytes/FLOP ~2.5x:
// - 32 q-rows/wave (128 q/block, grid 512): K/V fragments loaded once into
//   regs, reused for both q-groups -> per-q LDS reads halve.
// - P stays in REGISTERS: k<->t bijection baked into Vtp global layout makes
//   the PV A-operand exactly the lane-local QK^T output (no pbuf, no
//   ds_write, no P re-read).
// - XCD swizzle kept (FETCH 12MB, near-ideal). Q pre-scaled; p = 2^s.
// ===========================================================================
__global__ __launch_bounds__(256) void attn_mfma2(
    const unsigned short* __restrict__ Qb,
    const unsigned short* __restrict__ Kb,
    const unsigned short* __restrict__ Vt,   // [B][H][K][S] permuted
    unsigned short* __restrict__ Cb)         // [B][S][H][K]
{
    __shared__ unsigned short ks[64 * 64];        // K tile [t][k] linear+swz
    __shared__ unsigned short vs[64 * 64];        // Vtp tile [d][kappa] +swz

    // XCD-aware bijective swizzle: nwg=512, 8 XCDs, chunk=64 (= 4 full bh).
    const int bid = blockIdx.x;
    const int lid = (bid & 7) * 64 + (bid >> 3);
    const int qt  = lid & 15;
    const int bh  = lid >> 4;
    const int h   = bh & 15;
    const int b   = bh >> 4;

    const int tid  = threadIdx.x;
    const int wv = tid >> 6, lane = tid & 63;
    const int quad = lane >> 4, l15 = lane & 15;
    const int l8 = lane >> 3;
    const int c8 = ((lane & 7) ^ l8) * 8;
    const int x7 = l15 & 7;

    const size_t base = ((size_t)(b * H_ + h)) * S_ * K_;   // Q,K and Vt extent

    // Q fragments: wave owns 32 q-rows = 2 groups of 16 (B-op of swapped QK^T)
    bf16x8 qf[2][2];
    #pragma unroll
    for (int g = 0; g < 2; ++g) {
        const int qrow = qt * 128 + wv * 32 + g * 16 + l15;
        qf[g][0] = *(const bf16x8*)(Qb + base + (size_t)qrow * K_ + quad * 8);
        qf[g][1] = *(const bf16x8*)(Qb + base + (size_t)qrow * K_ + 32 + quad * 8);
    }

    f32x4 ctxa[2][4] = {};
    float li[2] = {0.0f, 0.0f};   // row-sum for q=l15 (replicated over quads)

    for (int it = 0; it < S_ / 64; ++it) {
        const int t0 = it * 64;
        __syncthreads();   // previous tile's reads complete before overwrite
        {
            const unsigned short* kg =
                Kb + base + (size_t)(t0 + wv * 16 + l8) * K_ + c8;
            gl_lds16(kg,          &ks[(wv * 2 + 0) * 512]);
            gl_lds16(kg + 8 * K_, &ks[(wv * 2 + 1) * 512]);
            const unsigned short* vg =
                Vt + base + (size_t)(wv * 16 + l8) * S_ + t0 + c8;
            gl_lds16(vg,          &vs[(wv * 2 + 0) * 512]);
            gl_lds16(vg + 8 * S_, &vs[(wv * 2 + 1) * 512]);
        }
        __syncthreads();   // vmcnt(0) drain

        // ---- S^T = K.Q^T : lane holds S[t=16tb+quad*4+r][q=l15], per g ----
        f32x4 sac[2][4] = {};
        __builtin_amdgcn_s_setprio(1);
        #pragma unroll
        for (int tb = 0; tb < 4; ++tb) {
            const bf16x8 kf0 = *(const bf16x8*)&ks[(tb * 16 + l15) * 64 + ((quad) ^ x7) * 8];
            const bf16x8 kf1 = *(const bf16x8*)&ks[(tb * 16 + l15) * 64 + ((4 + quad) ^ x7) * 8];
            #pragma unroll
            for (int g = 0; g < 2; ++g) {
                sac[g][tb] = __builtin_amdgcn_mfma_f32_16x16x32_bf16(kf0, qf[g][0], sac[g][tb], 0, 0, 0);
                sac[g][tb] = __builtin_amdgcn_mfma_f32_16x16x32_bf16(kf1, qf[g][1], sac[g][tb], 0, 0, 0);
            }
        }
        __builtin_amdgcn_s_setprio(0);

        // ---- softmax: p = 2^s; in-lane sum + cross-quad; pack A-frags ----
        bf16x8 pa[2][2];   // [g][kh] PV A-operand, fully lane-local
        #pragma unroll
        for (int g = 0; g < 2; ++g) {
            float ps[4][4];
            float rs = 0.0f;
            #pragma unroll
            for (int tb = 0; tb < 4; ++tb)
                #pragma unroll
                for (int r = 0; r < 4; ++r) {
                    const float p = fexp2(sac[g][tb][r]);
                    ps[tb][r] = p;
                    rs += p;
                }
            rs += __shfl_xor(rs, 16);
            rs += __shfl_xor(rs, 32);
            li[g] += rs;

            // A-frag element j of kh: j<4 -> ps[2kh][j], else ps[2kh+1][j-4]
            #pragma unroll
            for (int kh = 0; kh < 2; ++kh) {
                union { bf16x8 v; unsigned short s[8]; } u;
                u.s[0] = f2b(ps[2 * kh][0]);     u.s[1] = f2b(ps[2 * kh][1]);
                u.s[2] = f2b(ps[2 * kh][2]);     u.s[3] = f2b(ps[2 * kh][3]);
                u.s[4] = f2b(ps[2 * kh + 1][0]); u.s[5] = f2b(ps[2 * kh + 1][1]);
                u.s[6] = f2b(ps[2 * kh + 1][2]); u.s[7] = f2b(ps[2 * kh + 1][3]);
                pa[g][kh] = u.v;
            }
        }

        // ---- PV: ctx[q][d], A = pa (regs), B = Vtp rows; bfr reused 2g ----
        __builtin_amdgcn_s_setprio(1);
        #pragma unroll
        for (int kh = 0; kh < 2; ++kh)
            #pragma unroll
            for (int cb = 0; cb < 4; ++cb) {
                const bf16x8 bfr = *(const bf16x8*)&vs[(cb * 16 + l15) * 64 + ((kh * 4 + quad) ^ x7) * 8];
                #pragma unroll
                for (int g = 0; g < 2; ++g)
                    ctxa[g][cb] = __builtin_amdgcn_mfma_f32_16x16x32_bf16(pa[g][kh], bfr, ctxa[g][cb], 0, 0, 0);
            }
        __builtin_amdgcn_s_setprio(0);
    }

    // ---- epilogue: normalize (li fetched from lane q), write [bs][hk] ----
    #pragma unroll
    for (int g = 0; g < 2; ++g)
        #pragma unroll
        for (int r = 0; r < 4; ++r) {
            const float inv = 1.0f / __shfl(li[g], quad * 4 + r);
            const int s = qt * 128 + wv * 32 + g * 16 + quad * 4 + r;
            const size_t ob = (((size_t)(b * S_ + s)) * H_ + h) * K_;
            #pragma unroll
            for (int cb = 0; cb < 4; ++cb)
                Cb[ob + cb * 16 + l15] = f2b(ctxa[g][cb][r] * inv);
        }
}

// ===========================================================================
// Fallback attention (R5-verified): reads V [B][H][S][K], in-kernel
// transpose, running-max softmax. (Expects UNSCALED Q from qkv_proj.)
// ===========================================================================
__global__ __launch_bounds__(256) void attn_mfma_v1(
    const unsigned short* __restrict__ Qb,
    const unsigned short* __restrict__ Kb,
    const unsigned short* __restrict__ Vb,
    unsigned short* __restrict__ Cb)
{
    __shared__ unsigned short ks[64 * 72];
    __shared__ unsigned short vt[64 * 72];
    __shared__ unsigned short pbuf[4 * 16 * 72];

    const int b = blockIdx.z, h = blockIdx.y, qt = blockIdx.x;
    const int tid  = threadIdx.x;
    const int wave = tid >> 6, lane = tid & 63;
    const int quad = lane >> 4, l15 = lane & 15;

    const size_t base = ((size_t)(b * H_ + h)) * S_ * K_;

    const int qrow = qt * 64 + wave * 16 + l15;
    const bf16x8 qf0 = *(const bf16x8*)(Qb + base + (size_t)qrow * K_ + quad * 8);
    const bf16x8 qf1 = *(const bf16x8*)(Qb + base + (size_t)qrow * K_ + 32 + quad * 8);

    f32x4 ctxa[4] = {};
    float mi[4], li[4];
    #pragma unroll
    for (int r = 0; r < 4; ++r) { mi[r] = -INFINITY; li[r] = 0.0f; }

    unsigned short* pw = pbuf + wave * 16 * 72;

    for (int tb0 = 0; tb0 < S_; tb0 += 64) {
        __syncthreads();
        #pragma unroll
        for (int p = 0; p < 2; ++p) {
            const int idx = tid + p * 256;
            const int t = idx >> 3, c = idx & 7;
            *(uint4*)&ks[t * 72 + c * 8] =
                *(const uint4*)(Kb + base + (size_t)(tb0 + t) * K_ + c * 8);
        }
        #pragma unroll
        for (int p = 0; p < 2; ++p) {
            const int c = wave + p * 4;
            uint4 u = *(const uint4*)(Vb + base + (size_t)(tb0 + lane) * K_ + c * 8);
            const unsigned short* us = (const unsigned short*)&u;
            #pragma unroll
            for (int d = 0; d < 8; ++d)
                vt[(c * 8 + d) * 72 + lane] = us[d];
        }
        __syncthreads();

        f32x4 sac[4] = {};
        #pragma unroll
        for (int tb = 0; tb < 4; ++tb) {
            const bf16x8 kf0 = *(const bf16x8*)&ks[(tb * 16 + l15) * 72 + quad * 8];
            const bf16x8 kf1 = *(const bf16x8*)&ks[(tb * 16 + l15) * 72 + 32 + quad * 8];
            sac[tb] = __builtin_amdgcn_mfma_f32_16x16x32_bf16(qf0, kf0, sac[tb], 0, 0, 0);
            sac[tb] = __builtin_amdgcn_mfma_f32_16x16x32_bf16(qf1, kf1, sac[tb], 0, 0, 0);
        }

        float mnew[4], alpha[4];
        #pragma unroll
        for (int r = 0; r < 4; ++r) {
            float v = fmaxf(fmaxf(sac[0][r], sac[1][r]), fmaxf(sac[2][r], sac[3][r])) * 0.125f;
            v = fmaxf(v, __shfl_xor(v, 1));
            v = fmaxf(v, __shfl_xor(v, 2));
            v = fmaxf(v, __shfl_xor(v, 4));
            v = fmaxf(v, __shfl_xor(v, 8));
            mnew[r]  = fmaxf(mi[r], v);
            alpha[r] = __expf(mi[r] - mnew[r]);
            mi[r]    = mnew[r];
        }
        float pv[4][4], rs[4];
        #pragma unroll
        for (int r = 0; r < 4; ++r) rs[r] = 0.0f;
        #pragma unroll
        for (int tb = 0; tb < 4; ++tb)
            #pragma unroll
            for (int r = 0; r < 4; ++r) {
                const float p = __expf(sac[tb][r] * 0.125f - mnew[r]);
                pv[tb][r] = p;
                rs[r] += p;
            }
        #pragma unroll
        for (int r = 0; r < 4; ++r) {
            float s = rs[r];
            s += __shfl_xor(s, 1);
            s += __shfl_xor(s, 2);
            s += __shfl_xor(s, 4);
            s += __shfl_xor(s, 8);
            li[r] = li[r] * alpha[r] + s;
        }
        #pragma unroll
        for (int cb = 0; cb < 4; ++cb)
            #pragma unroll
            for (int r = 0; r < 4; ++r)
                ctxa[cb][r] *= alpha[r];

        #pragma unroll
        for (int tb = 0; tb < 4; ++tb)
            #pragma unroll
            for (int r = 0; r < 4; ++r)
                pw[(quad * 4 + r) * 72 + tb * 16 + l15] = f2b(pv[tb][r]);

        #pragma unroll
        for (int kh = 0; kh < 2; ++kh) {
            const bf16x8 af = *(const bf16x8*)&pw[l15 * 72 + kh * 32 + quad * 8];
            #pragma unroll
            for (int cb = 0; cb < 4; ++cb) {
                const bf16x8 bfr = *(const bf16x8*)&vt[(cb * 16 + l15) * 72 + kh * 32 + quad * 8];
                ctxa[cb] = __builtin_amdgcn_mfma_f32_16x16x32_bf16(af, bfr, ctxa[cb], 0, 0, 0);
            }
        }
    }

    #pragma unroll
    for (int r = 0; r < 4; ++r) {
        const float inv = 1.0f / li[r];
        const int s = qt * 64 + wave * 16 + quad * 4 + r;
        const size_t ob = (((size_t)(b * S_ + s)) * H_ + h) * K_;
        #pragma unroll
        for (int cb = 0; cb < 4; ++cb)
            Cb[ob + cb * 16 + l15] = f2b(ctxa[cb][r] * inv);
    }
}

// ===========================================================================
// Kernel C (MFMA): output projection + head sum.
// global_load_lds(16B) staging + double-buffer/prefetch (T3 2-phase).
// ===========================================================================
__global__ __launch_bounds__(256) void gemm_out(
    const unsigned short* __restrict__ ctx,   // bf16 [4096][1024]
    const unsigned short* __restrict__ Wot,   // bf16 [1024 d][1024 hk]
    float* __restrict__ out)                  // fp32 [4096][1024]
{
    __shared__ unsigned short cs[2][128 * 64];   // 32KB
    __shared__ unsigned short ws[2][64 * 64];    // 16KB

    const int nt = blockIdx.x, mt = blockIdx.y;
    const int tid = threadIdx.x;
    const int wv = tid >> 6, lane = tid & 63;
    const int quad = lane >> 4, l15 = lane & 15;
    const int l8 = lane >> 3;
    const int c8 = ((lane & 7) ^ l8) * 8;
    const int x7 = l15 & 7;
    const int m0 = mt * 128, n0 = nt * 64;

    f32x4 acc[2][4] = {};

    auto stage = [&](int bi, int k0) {
        const unsigned short* cg =
            ctx + (size_t)(m0 + wv * 32 + l8) * 1024 + k0 + c8;
        #pragma unroll
        for (int j = 0; j < 4; ++j)
            gl_lds16(cg + (size_t)j * 8 * 1024, &cs[bi][(wv * 4 + j) * 512]);
        const unsigned short* wg =
            Wot + (size_t)(n0 + wv * 16 + l8) * 1024 + k0 + c8;
        gl_lds16(wg,            &ws[bi][(wv * 2 + 0) * 512]);
        gl_lds16(wg + 8 * 1024, &ws[bi][(wv * 2 + 1) * 512]);
    };

    stage(0, 0);
    __syncthreads();

    for (int kt = 0; kt < 16; ++kt) {
        const int cur = kt & 1;
        if (kt < 15) stage(cur ^ 1, (kt + 1) * 64);

        const unsigned short* csc = cs[cur];
        const unsigned short* wsc = ws[cur];
        #pragma unroll
        for (int kh = 0; kh < 2; ++kh) {
            const int csw = ((kh * 4 + quad) ^ x7) * 8;
            const bf16x8 a0 = *(const bf16x8*)&csc[(wv * 32 + l15) * 64 + csw];
            const bf16x8 a1 = *(const bf16x8*)&csc[(wv * 32 + 16 + l15) * 64 + csw];
            #pragma unroll
            for (int nb = 0; nb < 4; ++nb) {
                const bf16x8 bfr = *(const bf16x8*)&wsc[(nb * 16 + l15) * 64 + csw];
                acc[0][nb] = __builtin_amdgcn_mfma_f32_16x16x32_bf16(a0, bfr, acc[0][nb], 0, 0, 0);
                acc[1][nb] = __builtin_amdgcn_mfma_f32_16x16x32_bf16(a1, bfr, acc[1][nb], 0, 0, 0);
            }
        }
        __syncthreads();
    }

    #pragma unroll
    for (int mf = 0; mf < 2; ++mf)
        #pragma unroll
        for (int r = 0; r < 4; ++r) {
            const int m = m0 + wv * 32 + mf * 16 + quad * 4 + r;
            #pragma unroll
            for (int nb = 0; nb < 4; ++nb)
                out[(size_t)m * 1024 + n0 + nb * 16 + l15] = acc[mf][nb][r];
        }
}

// ===========================================================================
// FALLBACK (32 MB ws): fp32 VALU projections (R5-verified)
// ===========================================================================
__global__ __launch_bounds__(256) void qkv_proj(
    const float* __restrict__ x, const float* __restrict__ Wq,
    const float* __restrict__ Wk, const float* __restrict__ Wv,
    unsigned short* __restrict__ Qo, unsigned short* __restrict__ Ko,
    unsigned short* __restrict__ Vo)
{
    __shared__ float xs[32][68];
    __shared__ float wqs[32][68];
    __shared__ float wks[32][68];
    __shared__ float wvs[32][68];

    const int h  = blockIdx.x;
    const int m0 = blockIdx.y * 64;
    const int t  = threadIdx.x;
    const int tx = t & 15, ty = t >> 4;
    const int xr = t >> 2, xc = (t & 3) * 8;
    const int wr = t >> 3, wc = (t & 7) * 8;

    float aq[4][4] = {}, ak[4][4] = {}, av[4][4] = {};
    const int wbase = h * D_ * K_;

    for (int d0 = 0; d0 < D_; d0 += 32) {
        __syncthreads();
        {
            const float* xf = x + (size_t)(m0 + xr) * D_ + d0 + xc;
            const float4 a = *(const float4*)xf;
            const float4 b = *(const float4*)(xf + 4);
            xs[xc + 0][xr] = a.x; xs[xc + 1][xr] = a.y;
            xs[xc + 2][xr] = a.z; xs[xc + 3][xr] = a.w;
            xs[xc + 4][xr] = b.x; xs[xc + 5][xr] = b.y;
            xs[xc + 6][xr] = b.z; xs[xc + 7][xr] = b.w;
        }
        {
            const size_t idx = (size_t)wbase + (size_t)(d0 + wr) * K_ + wc;
            *(float4*)&wqs[wr][wc]     = *(const float4*)&Wq[idx];
            *(float4*)&wqs[wr][wc + 4] = *(const float4*)&Wq[idx + 4];
            *(float4*)&wks[wr][wc]     = *(const float4*)&Wk[idx];
            *(float4*)&wks[wr][wc + 4] = *(const float4*)&Wk[idx + 4];
            *(float4*)&wvs[wr][wc]     = *(const float4*)&Wv[idx];
            *(float4*)&wvs[wr][wc + 4] = *(const float4*)&Wv[idx + 4];
        }
        __syncthreads();

        #pragma unroll 8
        for (int kk = 0; kk < 32; ++kk) {
            const float4 xv = *(const float4*)&xs[kk][ty * 4];
            const float4 q4 = *(const float4*)&wqs[kk][tx * 4];
            const float4 k4 = *(const float4*)&wks[kk][tx * 4];
            const float4 v4 = *(const float4*)&wvs[kk][tx * 4];
            const float xa[4] = {xv.x, xv.y, xv.z, xv.w};
            const float qa[4] = {q4.x, q4.y, q4.z, q4.w};
            const float ka[4] = {k4.x, k4.y, k4.z, k4.w};
            const float va[4] = {v4.x, v4.y, v4.z, v4.w};
            #pragma unroll
            for (int i = 0; i < 4; ++i)
                #pragma unroll
                for (int j = 0; j < 4; ++j) {
                    aq[i][j] += xa[i] * qa[j];
                    ak[i][j] += xa[i] * ka[j];
                    av[i][j] += xa[i] * va[j];
                }
        }
    }

    #pragma unroll
    for (int i = 0; i < 4; ++i) {
        const int m  = m0 + ty * 4 + i;
        const int bb = m >> 11;
        const int ss = m & (S_ - 1);
        const size_t base = (((size_t)(bb * H_ + h)) * S_ + ss) * K_ + tx * 4;
        ushort4 pq, pk, pv;
        pq.x = f2b(aq[i][0]); pq.y = f2b(aq[i][1]); pq.z = f2b(aq[i][2]); pq.w = f2b(aq[i][3]);
        pk.x = f2b(ak[i][0]); pk.y = f2b(ak[i][1]); pk.z = f2b(ak[i][2]); pk.w = f2b(ak[i][3]);
        pv.x = f2b(av[i][0]); pv.y = f2b(av[i][1]); pv.z = f2b(av[i][2]); pv.w = f2b(av[i][3]);
        *(ushort4*)&Qo[base] = pq;
        *(ushort4*)&Ko[base] = pk;
        *(ushort4*)&Vo[base] = pv;
    }
}

__global__ __launch_bounds__(256) void out_proj(
    const unsigned int* __restrict__ Cb, const float* __restrict__ Wo,
    float* __restrict__ out)
{
    __shared__ float cs[32][68];
    __shared__ float wos[32][68];

    const int n0 = blockIdx.x * 64;
    const int m0 = blockIdx.y * 64;
    const int t  = threadIdx.x;
    const int tx = t & 15, ty = t >> 4;
    const int xr = t >> 2, xc = (t & 3) * 8;
    const int wr = t >> 3, wc = (t & 7) * 8;

    float acc[4][4] = {};

    for (int k0 = 0; k0 < 1024; k0 += 32) {
        __syncthreads();
        {
            uint4 u = *(const uint4*)&Cb[((size_t)(m0 + xr) * 1024 + k0 + xc) >> 1];
            cs[xc + 0][xr] = bf_lo(u.x); cs[xc + 1][xr] = bf_hi(u.x);
            cs[xc + 2][xr] = bf_lo(u.y); cs[xc + 3][xr] = bf_hi(u.y);
            cs[xc + 4][xr] = bf_lo(u.z); cs[xc + 5][xr] = bf_hi(u.z);
            cs[xc + 6][xr] = bf_lo(u.w); cs[xc + 7][xr] = bf_hi(u.w);
        }
        {
            const float* wof = Wo + (size_t)(k0 + wr) * 1024 + n0 + wc;
            *(float4*)&wos[wr][wc]     = *(const float4*)wof;
            *(float4*)&wos[wr][wc + 4] = *(const float4*)(wof + 4);
        }
        __syncthreads();

        #pragma unroll 8
        for (int kk = 0; kk < 32; ++kk) {
            const float4 cv = *(const float4*)&cs[kk][ty * 4];
            const float4 wv = *(const float4*)&wos[kk][tx * 4];
            const float ca[4] = {cv.x, cv.y, cv.z, cv.w};
            const float wa[4] = {wv.x, wv.y, wv.z, wv.w};
            #pragma unroll
            for (int i = 0; i < 4; ++i)
                #pragma unroll
                for (int j = 0; j < 4; ++j)
                    acc[i][j] += ca[i] * wa[j];
        }
    }

    #pragma unroll
    for (int i = 0; i < 4; ++i) {
        const int m = m0 + ty * 4 + i;
        float4 p = make_float4(acc[i][0], acc[i][1], acc[i][2], acc[i][3]);
        *(float4*)&out[(size_t)m * 1024 + n0 + tx * 4] = p;
    }
}

// ===========================================================================
extern "C" void kernel_launch(void* const* d_in, const int* in_sizes, int n_in,
                              void* d_out, int out_size, void* d_ws, size_t ws_size,
                              hipStream_t stream)
{
    (void)in_sizes; (void)n_in; (void)out_size;
    const float* x  = (const float*)d_in[0];
    const float* Wq = (const float*)d_in[1];
    const float* Wk = (const float*)d_in[2];
    const float* Wv = (const float*)d_in[3];
    const float* Wo = (const float*)d_in[4];
    float* out = (float*)d_out;

    const size_t QKV_ELEMS = (size_t)B_ * H_ * S_ * K_;   // 4,194,304

    if (ws_size >= (size_t)40 * 1024 * 1024) {
        // ws layout (bf16 elems), exactly 40 MB:
        //  xb (8MB; aliased by ctx after gemm_qkv) | Wtq|Wtk|Wtv (2MB each) |
        //  Wot (2MB) | Q (8MB) | K (8MB) | Vt (8MB, [B][H][K][S] permuted)
        unsigned short* xb  = (unsigned short*)d_ws;
        unsigned short* Wtq = xb  + (size_t)4096 * 1024;
        unsigned short* Wtk = Wtq + (size_t)16 * 64 * 1024;
        unsigned short* Wtv = Wtk + (size_t)16 * 64 * 1024;
        unsigned short* Wot = Wtv + (size_t)16 * 64 * 1024;
        unsigned short* Qb  = Wot + (size_t)1024 * 1024;
        unsigned short* Kb  = Qb + QKV_ELEMS;
        unsigned short* Vtb = Kb + QKV_ELEMS;
        unsigned short* Cb  = xb;   // alias: xb dead after gemm_qkv

        cvt_bf16_4<<<4096, 256, 0, stream>>>(x, xb);
        transpose_cvt3<<<dim3(1, 16, 48), 256, 0, stream>>>(
            Wq, Wk, Wv, Wtq, Wtk, Wtv, 1024, 64, 16);
        transpose_cvt3<<<dim3(16, 16, 1), 256, 0, stream>>>(
            Wo, Wo, Wo, Wot, Wot, Wot, 1024, 1024, 1);

        gemm_qkv<<<dim3(16, 32), 256, 0, stream>>>(xb, Wtq, Wtk, Wtv, Qb, Kb, Vtb);
        attn_mfma2<<<dim3(512), 256, 0, stream>>>(Qb, Kb, Vtb, Cb);
        gemm_out<<<dim3(16, 32), 256, 0, stream>>>(Cb, Wot, out);
    } else {
        // fallback (32 MB): Q | K | V | ctx   (R5-verified path)
        unsigned short* Qb = (unsigned short*)d_ws;
        unsigned short* Kb = Qb + QKV_ELEMS;
        unsigned short* Vb = Kb + QKV_ELEMS;
        unsigned short* Cb = Vb + QKV_ELEMS;

        qkv_proj<<<dim3(16, 64), 256, 0, stream>>>(x, Wq, Wk, Wv, Qb, Kb, Vb);
        attn_mfma_v1<<<dim3(32, 16, 2), 256, 0, stream>>>(Qb, Kb, Vb, Cb);
        out_proj<<<dim3(16, 64), 256, 0, stream>>>((const unsigned int*)Cb, Wo, out);
    }
}

// Round 5
// 180.266 us; speedup vs baseline: 1.0832x; 1.0327x over previous
//
#include <hip/hip_runtime.h>
#include <hip/hip_bf16.h>

// Shapes (fixed by reference): B=2, S=2048, D=1024, H=16, K(d_head)=64
// Inputs FP32, output FP32. Intermediates bf16 in d_ws (40 MB layout).
#define B_ 2
#define S_ 2048
#define D_ 1024
#define H_ 16
#define K_ 64
// BS = 4096, HK = 1024

// softmax scale folded into Q at projection time: 0.125 * log2(e)
#define QSCALE 0.18033688f

typedef __attribute__((ext_vector_type(4))) float f32x4;
typedef __attribute__((ext_vector_type(8))) short bf16x8;

__device__ __forceinline__ float bf_lo(unsigned int u) {
    union { float f; unsigned int i; } c; c.i = u << 16; return c.f;
}
__device__ __forceinline__ float bf_hi(unsigned int u) {
    union { float f; unsigned int i; } c; c.i = u & 0xffff0000u; return c.f;
}
__device__ __forceinline__ unsigned short f2b(float f) {
    __hip_bfloat16 h = __float2bfloat16(f);   // RNE
    union { __hip_bfloat16 h; unsigned short s; } c; c.h = h; return c.s;
}

// 2^x via v_exp_f32 (scale pre-folded into Q upstream)
__device__ __forceinline__ float fexp2(float x) {
#if __has_builtin(__builtin_amdgcn_exp2f)
    return __builtin_amdgcn_exp2f(x);
#else
    float r; asm("v_exp_f32 %0, %1" : "=v"(r) : "v"(x)); return r;
#endif
}

// Direct global->LDS, 16B per lane. LDS dest is wave-uniform base + lane*16
// (linear).
__device__ __forceinline__ void gl_lds16(const unsigned short* g, const unsigned short* l)
{
    __builtin_amdgcn_global_load_lds(
        (const __attribute__((address_space(1))) unsigned int*)(unsigned long long)g,
        (__attribute__((address_space(3))) unsigned int*)(unsigned int)(unsigned long long)l,
        16, 0, 0);
}

// ===========================================================================
// PREP KERNELS
// ===========================================================================

// fp32 -> bf16, 4 elems/thread.
__global__ __launch_bounds__(256) void cvt_bf16_4(
    const float* __restrict__ in, unsigned short* __restrict__ out)
{
    const int i = (blockIdx.x * 256 + threadIdx.x) * 4;
    const float4 v = *(const float4*)(in + i);
    ushort4 o;
    o.x = f2b(v.x); o.y = f2b(v.y); o.z = f2b(v.z); o.w = f2b(v.w);
    *(ushort4*)(out + i) = o;
}

// Transpose+convert: in fp32 [R][C] row-major -> out bf16 [C][R].
__global__ __launch_bounds__(256) void transpose_cvt3(
    const float* __restrict__ A0, const float* __restrict__ A1,
    const float* __restrict__ A2,
    unsigned short* __restrict__ O0, unsigned short* __restrict__ O1,
    unsigned short* __restrict__ O2,
    int R, int C, int mats_per_src)
{
    __shared__ float tl[64][65];
    const int z = blockIdx.z;
    const int src = z / mats_per_src, m = z - src * mats_per_src;
    const float* in = (src == 0) ? A0 : (src == 1) ? A1 : A2;
    unsigned short* out = (src == 0) ? O0 : (src == 1) ? O1 : O2;
    const size_t mb = (size_t)m * R * C;
    const int c0 = blockIdx.x * 64, r0 = blockIdx.y * 64;
    const int t = threadIdx.x;

    #pragma unroll
    for (int p = 0; p < 4; ++p) {
        const int idx = p * 256 + t;
        const int r = idx >> 4, cc = (idx & 15) * 4;
        const float4 v = *(const float4*)(in + mb + (size_t)(r0 + r) * C + c0 + cc);
        tl[r][cc] = v.x; tl[r][cc + 1] = v.y; tl[r][cc + 2] = v.z; tl[r][cc + 3] = v.w;
    }
    __syncthreads();
    const int c = t >> 2, rc = (t & 3) * 16;
    unsigned int u[8];
    #pragma unroll
    for (int j = 0; j < 8; ++j)
        u[j] = (unsigned int)f2b(tl[rc + 2 * j][c]) |
               ((unsigned int)f2b(tl[rc + 2 * j + 1][c]) << 16);
    unsigned short* op = out + mb + (size_t)(c0 + c) * R + r0 + rc;
    *(uint4*)op       = *(uint4*)&u[0];
    *(uint4*)(op + 8) = *(uint4*)&u[4];
}

// ===========================================================================
// Kernel A (MFMA): fused QKV projection.
// global_load_lds(16B) staging, linear LDS + XOR-swizzle (both sides),
// double-buffered tiles + prefetch (T3 2-phase).
// Q written PRE-SCALED by QSCALE. Q,K [B][H][S][K].
// V written transposed AND k-permuted within 32-col blocks (Vtp):
//   store pos kappa of value t: kappa{4:3}=t{3:2}, kappa{2}=t{4}, kappa{1:0}=t{1:0}
// so attn's PV A-operand is lane-local (P never goes through LDS).
// ===========================================================================
__global__ __launch_bounds__(256) void gemm_qkv(
    const unsigned short* __restrict__ xb,    // bf16 [4096][1024]
    const unsigned short* __restrict__ Wtq,   // bf16 [16][64][1024]
    const unsigned short* __restrict__ Wtk,
    const unsigned short* __restrict__ Wtv,
    unsigned short* __restrict__ Qo,          // bf16 [B][H][S][K]
    unsigned short* __restrict__ Ko,          // bf16 [B][H][S][K]
    unsigned short* __restrict__ Vto)         // bf16 [B][H][K][S] (permuted)
{
    __shared__ unsigned short xs[2][128 * 64];    // 32KB [m][k] linear, swz
    __shared__ unsigned short ws[2][3][64 * 64];  // 48KB [n][k] per W, swz

    const int h = blockIdx.x, mt = blockIdx.y;
    const int tid = threadIdx.x;
    const int wv = tid >> 6, lane = tid & 63;
    const int quad = lane >> 4, l15 = lane & 15;
    const int l8 = lane >> 3;
    const int c8 = ((lane & 7) ^ l8) * 8;   // pre-swizzled source col (elems)
    const int x7 = l15 & 7;                 // read-side XOR key
    const int m0 = mt * 128;

    const unsigned short* wsrc[3] = {
        Wtq + (size_t)h * 65536, Wtk + (size_t)h * 65536, Wtv + (size_t)h * 65536 };

    f32x4 acc[3][2][4] = {};   // [out][mfrag][nfrag]

    auto stage = [&](int bi, int k0) {
        const unsigned short* xg =
            xb + (size_t)(m0 + wv * 32 + l8) * 1024 + k0 + c8;
        #pragma unroll
        for (int j = 0; j < 4; ++j)
            gl_lds16(xg + (size_t)j * 8 * 1024, &xs[bi][(wv * 4 + j) * 512]);
        #pragma unroll
        for (int w = 0; w < 3; ++w) {
            const unsigned short* wg =
                wsrc[w] + (size_t)(wv * 16 + l8) * 1024 + k0 + c8;
            gl_lds16(wg,            &ws[bi][w][(wv * 2 + 0) * 512]);
            gl_lds16(wg + 8 * 1024, &ws[bi][w][(wv * 2 + 1) * 512]);
        }
    };

    stage(0, 0);
    __syncthreads();   // compiler emits vmcnt(0) drain here

    for (int kt = 0; kt < 16; ++kt) {
        const int cur = kt & 1;
        if (kt < 15) stage(cur ^ 1, (kt + 1) * 64);   // prefetch next tile

        const unsigned short* xsc = xs[cur];
        #pragma unroll
        for (int kh = 0; kh < 2; ++kh) {
            const int csw = ((kh * 4 + quad) ^ x7) * 8;   // rows used have r&7==x7
            const bf16x8 a0 = *(const bf16x8*)&xsc[(wv * 32 + l15) * 64 + csw];
            const bf16x8 a1 = *(const bf16x8*)&xsc[(wv * 32 + 16 + l15) * 64 + csw];
            #pragma unroll
            for (int nb = 0; nb < 4; ++nb) {
                #pragma unroll
                for (int w = 0; w < 3; ++w) {
                    const bf16x8 bfr = *(const bf16x8*)&ws[cur][w][(nb * 16 + l15) * 64 + csw];
                    acc[w][0][nb] = __builtin_amdgcn_mfma_f32_16x16x32_bf16(a0, bfr, acc[w][0][nb], 0, 0, 0);
                    acc[w][1][nb] = __builtin_amdgcn_mfma_f32_16x16x32_bf16(a1, bfr, acc[w][1][nb], 0, 0, 0);
                }
            }
        }
        __syncthreads();   // drains this iter's prefetch (issued pre-compute)
    }

    // Q (scaled), K epilogue: C row = quad*4+reg, col = l15. [B][H][S][K]
    #pragma unroll
    for (int mf = 0; mf < 2; ++mf)
        #pragma unroll
        for (int r = 0; r < 4; ++r) {
            const int s  = m0 + wv * 32 + mf * 16 + quad * 4 + r;
            const int bb = s >> 11;
            const int ss = s & (S_ - 1);
            const size_t base = (((size_t)(bb * H_ + h)) * S_ + ss) * K_;
            #pragma unroll
            for (int nb = 0; nb < 4; ++nb) {
                Qo[base + nb * 16 + l15] = f2b(acc[0][mf][nb][r] * QSCALE);
                Ko[base + nb * 16 + l15] = f2b(acc[1][mf][nb][r]);
            }
        }

    // V epilogue: transposed + k-permuted. Lane's 4 consecutive s values
    // (s = sb + r, sb = ...+quad*4, r=0..3) land at permuted inner pos
    // kappa = quad*8 + mf*4 + r within the 32-block -> still one 8B store.
    {
        const int sb32 = m0 + wv * 32;           // 32-aligned block base
        const int bb   = sb32 >> 11;
        const int ssb  = sb32 & (S_ - 1);        // 32-aligned
        #pragma unroll
        for (int mf = 0; mf < 2; ++mf) {
            const int kap = quad * 8 + mf * 4;   // permuted offset in 32-block
            #pragma unroll
            for (int nb = 0; nb < 4; ++nb) {
                const int k = nb * 16 + l15;
                const size_t vaddr = (((size_t)(bb * H_ + h)) * K_ + k) * S_ + ssb + kap;
                uint2 u;
                u.x = (unsigned int)f2b(acc[2][mf][nb][0]) | ((unsigned int)f2b(acc[2][mf][nb][1]) << 16);
                u.y = (unsigned int)f2b(acc[2][mf][nb][2]) | ((unsigned int)f2b(acc[2][mf][nb][3]) << 16);
                *(uint2*)&Vto[vaddr] = u;
            }
        }
    }
}

// ===========================================================================
// Kernel B (MFMA flash attention v8):
// R4 post-mortem: v7 (P-in-reg, conflicts=0, LDS light) is latency-bound:
// ~1500 cyc/tile of exposed staging drain (single-buffered barrier->stage->
// vmcnt0->compute, 2 blocks/CU). Fix now that LDS-BW headroom exists:
// - double-buffered K/V + prefetch-before-compute; ONE barrier per tile.
//   vmcnt(0) drain lands after the tile's MFMA+VALU instead of before.
// - li cross-quad reduction deferred to epilogue (li is a pure running sum;
//   removes 2 DS-shuffles from every tile's softmax critical path).
// - 32 q/wave, Vtp k-permuted layout, XCD swizzle, Q pre-scaled, p=2^s.
// ===========================================================================
__global__ __launch_bounds__(256) void attn_mfma2(
    const unsigned short* __restrict__ Qb,
    const unsigned short* __restrict__ Kb,
    const unsigned short* __restrict__ Vt,   // [B][H][K][S] permuted
    unsigned short* __restrict__ Cb)         // [B][S][H][K]
{
    __shared__ unsigned short ks[2][64 * 64];     // K tile [t][k] linear+swz
    __shared__ unsigned short vs[2][64 * 64];     // Vtp tile [d][kappa] +swz

    // XCD-aware bijective swizzle: nwg=512, 8 XCDs, chunk=64 (= 4 full bh).
    const int bid = blockIdx.x;
    const int lid = (bid & 7) * 64 + (bid >> 3);
    const int qt  = lid & 15;
    const int bh  = lid >> 4;
    const int h   = bh & 15;
    const int b   = bh >> 4;

    const int tid  = threadIdx.x;
    const int wv = tid >> 6, lane = tid & 63;
    const int quad = lane >> 4, l15 = lane & 15;
    const int l8 = lane >> 3;
    const int c8 = ((lane & 7) ^ l8) * 8;
    const int x7 = l15 & 7;

    const size_t base = ((size_t)(b * H_ + h)) * S_ * K_;   // Q,K and Vt extent

    // Q fragments: wave owns 32 q-rows = 2 groups of 16 (B-op of swapped QK^T)
    bf16x8 qf[2][2];
    #pragma unroll
    for (int g = 0; g < 2; ++g) {
        const int qrow = qt * 128 + wv * 32 + g * 16 + l15;
        qf[g][0] = *(const bf16x8*)(Qb + base + (size_t)qrow * K_ + quad * 8);
        qf[g][1] = *(const bf16x8*)(Qb + base + (size_t)qrow * K_ + 32 + quad * 8);
    }

    f32x4 ctxa[2][4] = {};
    float li[2] = {0.0f, 0.0f};   // PER-QUAD partial row-sum (reduced at end)

    auto stage = [&](int bi, int t0) {
        const unsigned short* kg =
            Kb + base + (size_t)(t0 + wv * 16 + l8) * K_ + c8;
        gl_lds16(kg,          &ks[bi][(wv * 2 + 0) * 512]);
        gl_lds16(kg + 8 * K_, &ks[bi][(wv * 2 + 1) * 512]);
        const unsigned short* vg =
            Vt + base + (size_t)(wv * 16 + l8) * S_ + t0 + c8;
        gl_lds16(vg,          &vs[bi][(wv * 2 + 0) * 512]);
        gl_lds16(vg + 8 * S_, &vs[bi][(wv * 2 + 1) * 512]);
    };

    stage(0, 0);
    __syncthreads();   // vmcnt(0) drain of prologue stage

    for (int it = 0; it < S_ / 64; ++it) {
        const int cur = it & 1;
        if (it < S_ / 64 - 1) stage(cur ^ 1, (it + 1) * 64);   // prefetch

        const unsigned short* ksc = ks[cur];
        const unsigned short* vsc = vs[cur];

        // ---- S^T = K.Q^T : lane holds S[t=16tb+quad*4+r][q=l15], per g ----
        f32x4 sac[2][4] = {};
        __builtin_amdgcn_s_setprio(1);
        #pragma unroll
        for (int tb = 0; tb < 4; ++tb) {
            const bf16x8 kf0 = *(const bf16x8*)&ksc[(tb * 16 + l15) * 64 + ((quad) ^ x7) * 8];
            const bf16x8 kf1 = *(const bf16x8*)&ksc[(tb * 16 + l15) * 64 + ((4 + quad) ^ x7) * 8];
            #pragma unroll
            for (int g = 0; g < 2; ++g) {
                sac[g][tb] = __builtin_amdgcn_mfma_f32_16x16x32_bf16(kf0, qf[g][0], sac[g][tb], 0, 0, 0);
                sac[g][tb] = __builtin_amdgcn_mfma_f32_16x16x32_bf16(kf1, qf[g][1], sac[g][tb], 0, 0, 0);
            }
        }
        __builtin_amdgcn_s_setprio(0);

        // ---- softmax: p = 2^s; in-lane partial sum only; pack A-frags ----
        bf16x8 pa[2][2];   // [g][kh] PV A-operand, fully lane-local
        #pragma unroll
        for (int g = 0; g < 2; ++g) {
            float ps[4][4];
            float rs = 0.0f;
            #pragma unroll
            for (int tb = 0; tb < 4; ++tb)
                #pragma unroll
                for (int r = 0; r < 4; ++r) {
                    const float p = fexp2(sac[g][tb][r]);
                    ps[tb][r] = p;
                    rs += p;
                }
            li[g] += rs;   // per-quad partial; cross-quad reduce deferred

            // A-frag element j of kh: j<4 -> ps[2kh][j], else ps[2kh+1][j-4]
            #pragma unroll
            for (int kh = 0; kh < 2; ++kh) {
                union { bf16x8 v; unsigned short s[8]; } u;
                u.s[0] = f2b(ps[2 * kh][0]);     u.s[1] = f2b(ps[2 * kh][1]);
                u.s[2] = f2b(ps[2 * kh][2]);     u.s[3] = f2b(ps[2 * kh][3]);
                u.s[4] = f2b(ps[2 * kh + 1][0]); u.s[5] = f2b(ps[2 * kh + 1][1]);
                u.s[6] = f2b(ps[2 * kh + 1][2]); u.s[7] = f2b(ps[2 * kh + 1][3]);
                pa[g][kh] = u.v;
            }
        }

        // ---- PV: ctx[q][d], A = pa (regs), B = Vtp rows; bfr reused 2g ----
        __builtin_amdgcn_s_setprio(1);
        #pragma unroll
        for (int kh = 0; kh < 2; ++kh)
            #pragma unroll
            for (int cb = 0; cb < 4; ++cb) {
                const bf16x8 bfr = *(const bf16x8*)&vsc[(cb * 16 + l15) * 64 + ((kh * 4 + quad) ^ x7) * 8];
                #pragma unroll
                for (int g = 0; g < 2; ++g)
                    ctxa[g][cb] = __builtin_amdgcn_mfma_f32_16x16x32_bf16(pa[g][kh], bfr, ctxa[g][cb], 0, 0, 0);
            }
        __builtin_amdgcn_s_setprio(0);

        __syncthreads();   // drains this iter's prefetch; protects buf reuse
    }

    // ---- epilogue: reduce li across quads ONCE, normalize, write ----
    #pragma unroll
    for (int g = 0; g < 2; ++g) {
        float lf = li[g];
        lf += __shfl_xor(lf, 16);
        lf += __shfl_xor(lf, 32);
        #pragma unroll
        for (int r = 0; r < 4; ++r) {
            const float inv = 1.0f / __shfl(lf, quad * 4 + r);
            const int s = qt * 128 + wv * 32 + g * 16 + quad * 4 + r;
            const size_t ob = (((size_t)(b * S_ + s)) * H_ + h) * K_;
            #pragma unroll
            for (int cb = 0; cb < 4; ++cb)
                Cb[ob + cb * 16 + l15] = f2b(ctxa[g][cb][r] * inv);
        }
    }
}

// ===========================================================================
// Fallback attention (R5-verified): reads V [B][H][S][K], in-kernel
// transpose, running-max softmax. (Expects UNSCALED Q from qkv_proj.)
// ===========================================================================
__global__ __launch_bounds__(256) void attn_mfma_v1(
    const unsigned short* __restrict__ Qb,
    const unsigned short* __restrict__ Kb,
    const unsigned short* __restrict__ Vb,
    unsigned short* __restrict__ Cb)
{
    __shared__ unsigned short ks[64 * 72];
    __shared__ unsigned short vt[64 * 72];
    __shared__ unsigned short pbuf[4 * 16 * 72];

    const int b = blockIdx.z, h = blockIdx.y, qt = blockIdx.x;
    const int tid  = threadIdx.x;
    const int wave = tid >> 6, lane = tid & 63;
    const int quad = lane >> 4, l15 = lane & 15;

    const size_t base = ((size_t)(b * H_ + h)) * S_ * K_;

    const int qrow = qt * 64 + wave * 16 + l15;
    const bf16x8 qf0 = *(const bf16x8*)(Qb + base + (size_t)qrow * K_ + quad * 8);
    const bf16x8 qf1 = *(const bf16x8*)(Qb + base + (size_t)qrow * K_ + 32 + quad * 8);

    f32x4 ctxa[4] = {};
    float mi[4], li[4];
    #pragma unroll
    for (int r = 0; r < 4; ++r) { mi[r] = -INFINITY; li[r] = 0.0f; }

    unsigned short* pw = pbuf + wave * 16 * 72;

    for (int tb0 = 0; tb0 < S_; tb0 += 64) {
        __syncthreads();
        #pragma unroll
        for (int p = 0; p < 2; ++p) {
            const int idx = tid + p * 256;
            const int t = idx >> 3, c = idx & 7;
            *(uint4*)&ks[t * 72 + c * 8] =
                *(const uint4*)(Kb + base + (size_t)(tb0 + t) * K_ + c * 8);
        }
        #pragma unroll
        for (int p = 0; p < 2; ++p) {
            const int c = wave + p * 4;
            uint4 u = *(const uint4*)(Vb + base + (size_t)(tb0 + lane) * K_ + c * 8);
            const unsigned short* us = (const unsigned short*)&u;
            #pragma unroll
            for (int d = 0; d < 8; ++d)
                vt[(c * 8 + d) * 72 + lane] = us[d];
        }
        __syncthreads();

        f32x4 sac[4] = {};
        #pragma unroll
        for (int tb = 0; tb < 4; ++tb) {
            const bf16x8 kf0 = *(const bf16x8*)&ks[(tb * 16 + l15) * 72 + quad * 8];
            const bf16x8 kf1 = *(const bf16x8*)&ks[(tb * 16 + l15) * 72 + 32 + quad * 8];
            sac[tb] = __builtin_amdgcn_mfma_f32_16x16x32_bf16(qf0, kf0, sac[tb], 0, 0, 0);
            sac[tb] = __builtin_amdgcn_mfma_f32_16x16x32_bf16(qf1, kf1, sac[tb], 0, 0, 0);
        }

        float mnew[4], alpha[4];
        #pragma unroll
        for (int r = 0; r < 4; ++r) {
            float v = fmaxf(fmaxf(sac[0][r], sac[1][r]), fmaxf(sac[2][r], sac[3][r])) * 0.125f;
            v = fmaxf(v, __shfl_xor(v, 1));
            v = fmaxf(v, __shfl_xor(v, 2));
            v = fmaxf(v, __shfl_xor(v, 4));
            v = fmaxf(v, __shfl_xor(v, 8));
            mnew[r]  = fmaxf(mi[r], v);
            alpha[r] = __expf(mi[r] - mnew[r]);
            mi[r]    = mnew[r];
        }
        float pv[4][4], rs[4];
        #pragma unroll
        for (int r = 0; r < 4; ++r) rs[r] = 0.0f;
        #pragma unroll
        for (int tb = 0; tb < 4; ++tb)
            #pragma unroll
            for (int r = 0; r < 4; ++r) {
                const float p = __expf(sac[tb][r] * 0.125f - mnew[r]);
                pv[tb][r] = p;
                rs[r] += p;
            }
        #pragma unroll
        for (int r = 0; r < 4; ++r) {
            float s = rs[r];
            s += __shfl_xor(s, 1);
            s += __shfl_xor(s, 2);
            s += __shfl_xor(s, 4);
            s += __shfl_xor(s, 8);
            li[r] = li[r] * alpha[r] + s;
        }
        #pragma unroll
        for (int cb = 0; cb < 4; ++cb)
            #pragma unroll
            for (int r = 0; r < 4; ++r)
                ctxa[cb][r] *= alpha[r];

        #pragma unroll
        for (int tb = 0; tb < 4; ++tb)
            #pragma unroll
            for (int r = 0; r < 4; ++r)
                pw[(quad * 4 + r) * 72 + tb * 16 + l15] = f2b(pv[tb][r]);

        #pragma unroll
        for (int kh = 0; kh < 2; ++kh) {
            const bf16x8 af = *(const bf16x8*)&pw[l15 * 72 + kh * 32 + quad * 8];
            #pragma unroll
            for (int cb = 0; cb < 4; ++cb) {
                const bf16x8 bfr = *(const bf16x8*)&vt[(cb * 16 + l15) * 72 + kh * 32 + quad * 8];
                ctxa[cb] = __builtin_amdgcn_mfma_f32_16x16x32_bf16(af, bfr, ctxa[cb], 0, 0, 0);
            }
        }
    }

    #pragma unroll
    for (int r = 0; r < 4; ++r) {
        const float inv = 1.0f / li[r];
        const int s = qt * 64 + wave * 16 + quad * 4 + r;
        const size_t ob = (((size_t)(b * S_ + s)) * H_ + h) * K_;
        #pragma unroll
        for (int cb = 0; cb < 4; ++cb)
            Cb[ob + cb * 16 + l15] = f2b(ctxa[cb][r] * inv);
    }
}

// ===========================================================================
// Kernel C (MFMA): output projection + head sum.
// global_load_lds(16B) staging + double-buffer/prefetch (T3 2-phase).
// ===========================================================================
__global__ __launch_bounds__(256) void gemm_out(
    const unsigned short* __restrict__ ctx,   // bf16 [4096][1024]
    const unsigned short* __restrict__ Wot,   // bf16 [1024 d][1024 hk]
    float* __restrict__ out)                  // fp32 [4096][1024]
{
    __shared__ unsigned short cs[2][128 * 64];   // 32KB
    __shared__ unsigned short ws[2][64 * 64];    // 16KB

    const int nt = blockIdx.x, mt = blockIdx.y;
    const int tid = threadIdx.x;
    const int wv = tid >> 6, lane = tid & 63;
    const int quad = lane >> 4, l15 = lane & 15;
    const int l8 = lane >> 3;
    const int c8 = ((lane & 7) ^ l8) * 8;
    const int x7 = l15 & 7;
    const int m0 = mt * 128, n0 = nt * 64;

    f32x4 acc[2][4] = {};

    auto stage = [&](int bi, int k0) {
        const unsigned short* cg =
            ctx + (size_t)(m0 + wv * 32 + l8) * 1024 + k0 + c8;
        #pragma unroll
        for (int j = 0; j < 4; ++j)
            gl_lds16(cg + (size_t)j * 8 * 1024, &cs[bi][(wv * 4 + j) * 512]);
        const unsigned short* wg =
            Wot + (size_t)(n0 + wv * 16 + l8) * 1024 + k0 + c8;
        gl_lds16(wg,            &ws[bi][(wv * 2 + 0) * 512]);
        gl_lds16(wg + 8 * 1024, &ws[bi][(wv * 2 + 1) * 512]);
    };

    stage(0, 0);
    __syncthreads();

    for (int kt = 0; kt < 16; ++kt) {
        const int cur = kt & 1;
        if (kt < 15) stage(cur ^ 1, (kt + 1) * 64);

        const unsigned short* csc = cs[cur];
        const unsigned short* wsc = ws[cur];
        #pragma unroll
        for (int kh = 0; kh < 2; ++kh) {
            const int csw = ((kh * 4 + quad) ^ x7) * 8;
            const bf16x8 a0 = *(const bf16x8*)&csc[(wv * 32 + l15) * 64 + csw];
            const bf16x8 a1 = *(const bf16x8*)&csc[(wv * 32 + 16 + l15) * 64 + csw];
            #pragma unroll
            for (int nb = 0; nb < 4; ++nb) {
                const bf16x8 bfr = *(const bf16x8*)&wsc[(nb * 16 + l15) * 64 + csw];
                acc[0][nb] = __builtin_amdgcn_mfma_f32_16x16x32_bf16(a0, bfr, acc[0][nb], 0, 0, 0);
                acc[1][nb] = __builtin_amdgcn_mfma_f32_16x16x32_bf16(a1, bfr, acc[1][nb], 0, 0, 0);
            }
        }
        __syncthreads();
    }

    #pragma unroll
    for (int mf = 0; mf < 2; ++mf)
        #pragma unroll
        for (int r = 0; r < 4; ++r) {
            const int m = m0 + wv * 32 + mf * 16 + quad * 4 + r;
            #pragma unroll
            for (int nb = 0; nb < 4; ++nb)
                out[(size_t)m * 1024 + n0 + nb * 16 + l15] = acc[mf][nb][r];
        }
}

// ===========================================================================
// FALLBACK (32 MB ws): fp32 VALU projections (R5-verified)
// ===========================================================================
__global__ __launch_bounds__(256) void qkv_proj(
    const float* __restrict__ x, const float* __restrict__ Wq,
    const float* __restrict__ Wk, const float* __restrict__ Wv,
    unsigned short* __restrict__ Qo, unsigned short* __restrict__ Ko,
    unsigned short* __restrict__ Vo)
{
    __shared__ float xs[32][68];
    __shared__ float wqs[32][68];
    __shared__ float wks[32][68];
    __shared__ float wvs[32][68];

    const int h  = blockIdx.x;
    const int m0 = blockIdx.y * 64;
    const int t  = threadIdx.x;
    const int tx = t & 15, ty = t >> 4;
    const int xr = t >> 2, xc = (t & 3) * 8;
    const int wr = t >> 3, wc = (t & 7) * 8;

    float aq[4][4] = {}, ak[4][4] = {}, av[4][4] = {};
    const int wbase = h * D_ * K_;

    for (int d0 = 0; d0 < D_; d0 += 32) {
        __syncthreads();
        {
            const float* xf = x + (size_t)(m0 + xr) * D_ + d0 + xc;
            const float4 a = *(const float4*)xf;
            const float4 b = *(const float4*)(xf + 4);
            xs[xc + 0][xr] = a.x; xs[xc + 1][xr] = a.y;
            xs[xc + 2][xr] = a.z; xs[xc + 3][xr] = a.w;
            xs[xc + 4][xr] = b.x; xs[xc + 5][xr] = b.y;
            xs[xc + 6][xr] = b.z; xs[xc + 7][xr] = b.w;
        }
        {
            const size_t idx = (size_t)wbase + (size_t)(d0 + wr) * K_ + wc;
            *(float4*)&wqs[wr][wc]     = *(const float4*)&Wq[idx];
            *(float4*)&wqs[wr][wc + 4] = *(const float4*)&Wq[idx + 4];
            *(float4*)&wks[wr][wc]     = *(const float4*)&Wk[idx];
            *(float4*)&wks[wr][wc + 4] = *(const float4*)&Wk[idx + 4];
            *(float4*)&wvs[wr][wc]     = *(const float4*)&Wv[idx];
            *(float4*)&wvs[wr][wc + 4] = *(const float4*)&Wv[idx + 4];
        }
        __syncthreads();

        #pragma unroll 8
        for (int kk = 0; kk < 32; ++kk) {
            const float4 xv = *(const float4*)&xs[kk][ty * 4];
            const float4 q4 = *(const float4*)&wqs[kk][tx * 4];
            const float4 k4 = *(const float4*)&wks[kk][tx * 4];
            const float4 v4 = *(const float4*)&wvs[kk][tx * 4];
            const float xa[4] = {xv.x, xv.y, xv.z, xv.w};
            const float qa[4] = {q4.x, q4.y, q4.z, q4.w};
            const float ka[4] = {k4.x, k4.y, k4.z, k4.w};
            const float va[4] = {v4.x, v4.y, v4.z, v4.w};
            #pragma unroll
            for (int i = 0; i < 4; ++i)
                #pragma unroll
                for (int j = 0; j < 4; ++j) {
                    aq[i][j] += xa[i] * qa[j];
                    ak[i][j] += xa[i] * ka[j];
                    av[i][j] += xa[i] * va[j];
                }
        }
    }

    #pragma unroll
    for (int i = 0; i < 4; ++i) {
        const int m  = m0 + ty * 4 + i;
        const int bb = m >> 11;
        const int ss = m & (S_ - 1);
        const size_t base = (((size_t)(bb * H_ + h)) * S_ + ss) * K_ + tx * 4;
        ushort4 pq, pk, pv;
        pq.x = f2b(aq[i][0]); pq.y = f2b(aq[i][1]); pq.z = f2b(aq[i][2]); pq.w = f2b(aq[i][3]);
        pk.x = f2b(ak[i][0]); pk.y = f2b(ak[i][1]); pk.z = f2b(ak[i][2]); pk.w = f2b(ak[i][3]);
        pv.x = f2b(av[i][0]); pv.y = f2b(av[i][1]); pv.z = f2b(av[i][2]); pv.w = f2b(av[i][3]);
        *(ushort4*)&Qo[base] = pq;
        *(ushort4*)&Ko[base] = pk;
        *(ushort4*)&Vo[base] = pv;
    }
}

__global__ __launch_bounds__(256) void out_proj(
    const unsigned int* __restrict__ Cb, const float* __restrict__ Wo,
    float* __restrict__ out)
{
    __shared__ float cs[32][68];
    __shared__ float wos[32][68];

    const int n0 = blockIdx.x * 64;
    const int m0 = blockIdx.y * 64;
    const int t  = threadIdx.x;
    const int tx = t & 15, ty = t >> 4;
    const int xr = t >> 2, xc = (t & 3) * 8;
    const int wr = t >> 3, wc = (t & 7) * 8;

    float acc[4][4] = {};

    for (int k0 = 0; k0 < 1024; k0 += 32) {
        __syncthreads();
        {
            uint4 u = *(const uint4*)&Cb[((size_t)(m0 + xr) * 1024 + k0 + xc) >> 1];
            cs[xc + 0][xr] = bf_lo(u.x); cs[xc + 1][xr] = bf_hi(u.x);
            cs[xc + 2][xr] = bf_lo(u.y); cs[xc + 3][xr] = bf_hi(u.y);
            cs[xc + 4][xr] = bf_lo(u.z); cs[xc + 5][xr] = bf_hi(u.z);
            cs[xc + 6][xr] = bf_lo(u.w); cs[xc + 7][xr] = bf_hi(u.w);
        }
        {
            const float* wof = Wo + (size_t)(k0 + wr) * 1024 + n0 + wc;
            *(float4*)&wos[wr][wc]     = *(const float4*)wof;
            *(float4*)&wos[wr][wc + 4] = *(const float4*)(wof + 4);
        }
        __syncthreads();

        #pragma unroll 8
        for (int kk = 0; kk < 32; ++kk) {
            const float4 cv = *(const float4*)&cs[kk][ty * 4];
            const float4 wv = *(const float4*)&wos[kk][tx * 4];
            const float ca[4] = {cv.x, cv.y, cv.z, cv.w};
            const float wa[4] = {wv.x, wv.y, wv.z, wv.w};
            #pragma unroll
            for (int i = 0; i < 4; ++i)
                #pragma unroll
                for (int j = 0; j < 4; ++j)
                    acc[i][j] += ca[i] * wa[j];
        }
    }

    #pragma unroll
    for (int i = 0; i < 4; ++i) {
        const int m = m0 + ty * 4 + i;
        float4 p = make_float4(acc[i][0], acc[i][1], acc[i][2], acc[i][3]);
        *(float4*)&out[(size_t)m * 1024 + n0 + tx * 4] = p;
    }
}

// ===========================================================================
extern "C" void kernel_launch(void* const* d_in, const int* in_sizes, int n_in,
                              void* d_out, int out_size, void* d_ws, size_t ws_size,
                              hipStream_t stream)
{
    (void)in_sizes; (void)n_in; (void)out_size;
    const float* x  = (const float*)d_in[0];
    const float* Wq = (const float*)d_in[1];
    const float* Wk = (const float*)d_in[2];
    const float* Wv = (const float*)d_in[3];
    const float* Wo = (const float*)d_in[4];
    float* out = (float*)d_out;

    const size_t QKV_ELEMS = (size_t)B_ * H_ * S_ * K_;   // 4,194,304

    if (ws_size >= (size_t)40 * 1024 * 1024) {
        // ws layout (bf16 elems), exactly 40 MB:
        //  xb (8MB; aliased by ctx after gemm_qkv) | Wtq|Wtk|Wtv (2MB each) |
        //  Wot (2MB) | Q (8MB) | K (8MB) | Vt (8MB, [B][H][K][S] permuted)
        unsigned short* xb  = (unsigned short*)d_ws;
        unsigned short* Wtq = xb  + (size_t)4096 * 1024;
        unsigned short* Wtk = Wtq + (size_t)16 * 64 * 1024;
        unsigned short* Wtv = Wtk + (size_t)16 * 64 * 1024;
        unsigned short* Wot = Wtv + (size_t)16 * 64 * 1024;
        unsigned short* Qb  = Wot + (size_t)1024 * 1024;
        unsigned short* Kb  = Qb + QKV_ELEMS;
        unsigned short* Vtb = Kb + QKV_ELEMS;
        unsigned short* Cb  = xb;   // alias: xb dead after gemm_qkv

        cvt_bf16_4<<<4096, 256, 0, stream>>>(x, xb);
        transpose_cvt3<<<dim3(1, 16, 48), 256, 0, stream>>>(
            Wq, Wk, Wv, Wtq, Wtk, Wtv, 1024, 64, 16);
        transpose_cvt3<<<dim3(16, 16, 1), 256, 0, stream>>>(
            Wo, Wo, Wo, Wot, Wot, Wot, 1024, 1024, 1);

        gemm_qkv<<<dim3(16, 32), 256, 0, stream>>>(xb, Wtq, Wtk, Wtv, Qb, Kb, Vtb);
        attn_mfma2<<<dim3(512), 256, 0, stream>>>(Qb, Kb, Vtb, Cb);
        gemm_out<<<dim3(16, 32), 256, 0, stream>>>(Cb, Wot, out);
    } else {
        // fallback (32 MB): Q | K | V | ctx   (R5-verified path)
        unsigned short* Qb = (unsigned short*)d_ws;
        unsigned short* Kb = Qb + QKV_ELEMS;
        unsigned short* Vb = Kb + QKV_ELEMS;
        unsigned short* Cb = Vb + QKV_ELEMS;

        qkv_proj<<<dim3(16, 64), 256, 0, stream>>>(x, Wq, Wk, Wv, Qb, Kb, Vb);
        attn_mfma_v1<<<dim3(32, 16, 2), 256, 0, stream>>>(Qb, Kb, Vb, Cb);
        out_proj<<<dim3(16, 64), 256, 0, stream>>>((const unsigned int*)Cb, Wo, out);
    }
}